// Round 6
// baseline (574.720 us; speedup 1.0000x reference)
//
#include <hip/hip_runtime.h>

typedef unsigned long long ull;

#define W_IMG 1920
#define H_IMG 1080
#define NBOX 4096

// ---- LDS layout (float offsets), total 9432 floats = 37728 B -> 4 blocks/CU ----
// conv1 phase: crop[3][24][28]=2016 | wt1[27][32]=864          | pool1[28][11][12]=3696
// conv2 phase: wt2[126][24]=3024 | buf2[24][81]=1944 | pool2[48][16]=768 | pool1 (live)
// head phase:  feat[576] | vec[128] | lout[6]   (reuse dead front region)
#define S_CROP  0
#define S_WT1   2016
#define S_WT2   0
#define S_BUF2  3024
#define S_POOL2 4968
#define S_POOL1 5736
#define S_FEAT  0
#define S_VEC   576
#define S_LOUT  704
#define SMEM_F  9432

__device__ __forceinline__ float4 ld4(const float* p) { return *(const float4*)p; }
__device__ __forceinline__ float prelu_f(float v, float a) { return v > 0.f ? v : a * v; }

// conv1(3x3,3->28) + maxpool(3,2,pad1) fused: one pooled output x 4 co per task.
// Raw conv max accumulated; bias+prelu applied after (monotone => bitwise-equal).
template<int SHIFT, int PMIN>
__device__ __forceinline__ void conv1_pool_task(const float* sm, int cq, int y0, int a0,
                                                float* mx) {
#pragma unroll
  for (int wy = 0; wy < 3; ++wy) {
    int y = y0 + wy;                 // conv output row, max 21
    if (y < 0) continue;             // pool top padding
    float acc0[3] = {0.f,0.f,0.f}, acc1[3] = {0.f,0.f,0.f};
    float acc2[3] = {0.f,0.f,0.f}, acc3[3] = {0.f,0.f,0.f};
#pragma unroll
    for (int c = 0; c < 3; ++c) {
#pragma unroll
      for (int kyy = 0; kyy < 3; ++kyy) {
        float r[8];
        const float* src = sm + S_CROP + c*672 + (y + kyy)*28 + a0;
        *(float4*)&r[0] = ld4(src);
        *(float4*)&r[4] = ld4(src + 4);
#pragma unroll
        for (int kxx = 0; kxx < 3; ++kxx) {
          float4 wq = ld4(sm + S_WT1 + (c*9 + kyy*3 + kxx)*32 + cq*4);
#pragma unroll
          for (int wx = PMIN; wx < 3; ++wx) {
            float v = r[SHIFT + wx + kxx];
            acc0[wx] += v*wq.x; acc1[wx] += v*wq.y;
            acc2[wx] += v*wq.z; acc3[wx] += v*wq.w;
          }
        }
      }
    }
#pragma unroll
    for (int wx = PMIN; wx < 3; ++wx) {
      mx[0] = fmaxf(mx[0], acc0[wx]);
      mx[1] = fmaxf(mx[1], acc1[wx]);
      mx[2] = fmaxf(mx[2], acc2[wx]);
      mx[3] = fmaxf(mx[3], acc3[wx]);
    }
  }
}

// conv2(3x3, 28->48): 4 co x P positions, K split over lane pairs (ks),
// x split 5/4 across wave pairs (X0/A0 compile-time, wave-uniform).
template<int X0, int A0, int P>
__device__ __forceinline__ void conv2_body(const float* sm, int cqL, int y, int ks, int h,
                                           float* acc0, float* acc1, float* acc2, float* acc3) {
#pragma unroll 1
  for (int cc = 0; cc < 7; ++cc) {
    int cl = ks*7 + cc;            // k-index within staged half
    int c  = h*14 + cl;            // global input channel
#pragma unroll
    for (int ky = 0; ky < 3; ++ky) {
      float rw[8];
      const float* src = sm + S_POOL1 + c*132 + (y + ky)*12 + A0;
      *(float4*)&rw[0] = ld4(src);
      *(float4*)&rw[4] = ld4(src + 4);
#pragma unroll
      for (int kx = 0; kx < 3; ++kx) {
        float4 wq = ld4(sm + S_WT2 + ((cl*3 + ky)*3 + kx)*24 + cqL*4);
#pragma unroll
        for (int p = 0; p < P; ++p) {
          float v = rw[X0 - A0 + p + kx];
          acc0[p] += v*wq.x; acc1[p] += v*wq.y;
          acc2[p] += v*wq.z; acc3[p] += v*wq.w;
        }
      }
    }
  }
}

template<int X0, int P>
__device__ __forceinline__ void conv2_finish(float* sm, int cqL, int y, int ks, int ch,
                                             const float* __restrict__ b2,
                                             const float* __restrict__ a2,
                                             float* acc0, float* acc1, float* acc2, float* acc3) {
#pragma unroll
  for (int p = 0; p < P; ++p) {
    acc0[p] += __shfl_xor(acc0[p], 1, 64);
    acc1[p] += __shfl_xor(acc1[p], 1, 64);
    acc2[p] += __shfl_xor(acc2[p], 1, 64);
    acc3[p] += __shfl_xor(acc3[p], 1, 64);
  }
  if (ks == 0) {
    float4 bq = ld4(b2 + ch*24 + cqL*4);
    float4 aq = ld4(a2 + ch*24 + cqL*4);
#pragma unroll
    for (int p = 0; p < P; ++p) {
      sm[S_BUF2 + (cqL*4+0)*81 + y*9 + X0 + p] = prelu_f(acc0[p] + bq.x, aq.x);
      sm[S_BUF2 + (cqL*4+1)*81 + y*9 + X0 + p] = prelu_f(acc1[p] + bq.y, aq.y);
      sm[S_BUF2 + (cqL*4+2)*81 + y*9 + X0 + p] = prelu_f(acc2[p] + bq.z, aq.z);
      sm[S_BUF2 + (cqL*4+3)*81 + y*9 + X0 + p] = prelu_f(acc3[p] + bq.w, aq.w);
    }
  }
}

__global__ __launch_bounds__(256, 4) void cnn_kernel(
    const float* __restrict__ image, const float* __restrict__ bboxes,
    const float* __restrict__ w1, const float* __restrict__ b1, const float* __restrict__ a1,
    const float* __restrict__ w2, const float* __restrict__ b2, const float* __restrict__ a2,
    const float* __restrict__ w3, const float* __restrict__ b3, const float* __restrict__ a3,
    const float* __restrict__ w4, const float* __restrict__ b4, const float* __restrict__ a4,
    const float* __restrict__ w5a, const float* __restrict__ b5a,
    const float* __restrict__ w5b, const float* __restrict__ b5b,
    float* __restrict__ boxes, float* __restrict__ scores)
{
  __shared__ float sm[SMEM_F];
  __shared__ int s_ix[24], s_iy[24];
  const int tid = threadIdx.x;
  const int n = blockIdx.x;
  const float lo = -__builtin_inff();

  // ---- Phase A: crop indices + conv1 weight transpose stage ----
  if (tid < 24) {
    int x1 = min(max((int)bboxes[n*4+0], 0), W_IMG);
    int x2 = min(max((int)bboxes[n*4+2], 0), W_IMG);
    s_ix[tid] = min(max(x1 + (tid*(x2-x1))/24, 0), W_IMG-1);
  } else if (tid >= 64 && tid < 88) {
    int j = tid - 64;
    int y1 = min(max((int)bboxes[n*4+1], 0), H_IMG);
    int y2 = min(max((int)bboxes[n*4+3], 0), H_IMG);
    s_iy[j] = min(max(y1 + (j*(y2-y1))/24, 0), H_IMG-1);
  }
  for (int d = tid; d < 756; d += 256) {
    int k = d / 28, co = d % 28;
    sm[S_WT1 + k*32 + co] = w1[co*27 + k];
  }
  __syncthreads();
  // ---- crop + normalize: crop[c][y][x], row stride 28 ----
  for (int e = tid; e < 1728; e += 256) {
    int c = e / 576, rr = e % 576, y = rr / 24, x = rr % 24;
    float v = image[(s_iy[y]*W_IMG + s_ix[x])*3 + c];
    sm[S_CROP + c*672 + y*28 + x] = (v - 127.5f) * 0.0078125f;
  }
  __syncthreads();

  // ---- Phase B: conv1+pool fused, WAVE-UNIFORM px-class scheduling ----
  // 16 wave-slots: 0..6 odd px (SHIFT=1), 7..13 even px>=2 (SHIFT=3), 14..15 px=0 (SHIFT=-1).
  // Each wave runs 4 slots; class branch is wave-uniform (no intra-wave divergence).
  {
    const int wv = tid >> 6, lane = tid & 63;
#pragma unroll 1
    for (int k = 0; k < 4; ++k) {
      const int s = 4*k + wv;          // wave-uniform slot 0..15
      float mx[4] = {lo, lo, lo, lo};
      int cq, py, px;
      bool valid;
      if (s < 7) {                     // odd px: x0 = 2px-1 == 1 mod 4
        int idx = s*64 + lane;
        valid = idx < 385;
        cq = idx % 7; int q = idx / 7; if (q > 54) q = 54;
        py = q / 5; px = 2*(q % 5) + 1;
        conv1_pool_task<1,0>(sm, cq, 2*py - 1, (2*px - 1) & ~3, mx);
      } else if (s < 14) {             // even px>=2: x0 == 3 mod 4
        int idx = (s - 7)*64 + lane;
        valid = idx < 385;
        cq = idx % 7; int q = idx / 7; if (q > 54) q = 54;
        py = q / 5; px = 2*(q % 5) + 2;
        conv1_pool_task<3,0>(sm, cq, 2*py - 1, (2*px - 1) & ~3, mx);
      } else {                         // px == 0 (left edge)
        int idx = (s - 14)*64 + lane;
        valid = idx < 77;
        cq = idx % 7; py = idx / 7; if (py > 10) py = 10;
        px = 0;
        conv1_pool_task<-1,1>(sm, cq, 2*py - 1, 0, mx);
      }
      if (valid) {
        float4 bq = ld4(&b1[cq*4]);
        float4 aq = ld4(&a1[cq*4]);
        sm[S_POOL1 + (cq*4+0)*132 + py*12 + px] = prelu_f(mx[0] + bq.x, aq.x);
        sm[S_POOL1 + (cq*4+1)*132 + py*12 + px] = prelu_f(mx[1] + bq.y, aq.y);
        sm[S_POOL1 + (cq*4+2)*132 + py*12 + px] = prelu_f(mx[2] + bq.z, aq.z);
        sm[S_POOL1 + (cq*4+3)*132 + py*12 + px] = prelu_f(mx[3] + bq.w, aq.w);
      }
    }
  }
  __syncthreads();

  // ---- Phase D: conv2 (2 co-chunks x 2 K-half stages), 4 waves active:
  //      wave pair xh=tid>>7 splits 9 cols into 5/4; thread=(cqL,y,ks) ----
  const int xh  = tid >> 7;
  const int hid = tid & 127;
  const int ks  = hid & 1;
  const int r2  = hid >> 1;          // 0..63
  const int cy  = r2 % 9, cqL = r2 / 9;
  const bool act = (r2 < 54);
  for (int ch = 0; ch < 2; ++ch) {
    float acc0[5]={}, acc1[5]={}, acc2[5]={}, acc3[5]={};
#pragma unroll 1
    for (int h = 0; h < 2; ++h) {
      // stage wt2 K-half h (channels h*14..h*14+13), transposed [126 k][24 co]
      for (int d = tid; d < 1512; d += 256) {
        int co = d / 63, j = d % 63;
        float2 v = *(const float2*)&w2[(ch*24 + co)*252 + h*126 + 2*j];
        sm[S_WT2 + (2*j  )*24 + co] = v.x;
        sm[S_WT2 + (2*j+1)*24 + co] = v.y;
      }
      __syncthreads();
      if (act) {
        if (xh == 0) conv2_body<0,0,5>(sm, cqL, cy, ks, h, acc0, acc1, acc2, acc3);
        else         conv2_body<5,4,4>(sm, cqL, cy, ks, h, acc0, acc1, acc2, acc3);
      }
      __syncthreads();   // staged weights free for restage / buf2 write next
    }
    if (act) {
      if (xh == 0) conv2_finish<0,5>(sm, cqL, cy, ks, ch, b2, a2, acc0, acc1, acc2, acc3);
      else         conv2_finish<5,4>(sm, cqL, cy, ks, ch, b2, a2, acc0, acc1, acc2, acc3);
    }
    __syncthreads();
    for (int o = tid; o < 384; o += 256) {           // pool2 (3,2,pad0) for this chunk
      int cl = o / 16, rem = o % 16, pyy = rem / 4, pxx = rem % 4;
      float m = lo;
#pragma unroll
      for (int ky = 0; ky < 3; ++ky)
#pragma unroll
        for (int kx = 0; kx < 3; ++kx)
          m = fmaxf(m, sm[S_BUF2 + cl*81 + (2*pyy+ky)*9 + (2*pxx+kx)]);
      sm[S_POOL2 + (ch*24 + cl)*16 + rem] = m;
    }
    __syncthreads();
  }

  // ---- Phase F: conv3 (2x2, 48->64) -> feat[576] ----
  {
    int co = tid >> 2, c4 = tid & 3;
    float acc[9] = {};
    for (int cc = 0; cc < 12; ++cc) {
      int c = c4*12 + cc;
      float r[16];
      *(float4*)&r[0]  = ld4(sm + S_POOL2 + c*16);
      *(float4*)&r[4]  = ld4(sm + S_POOL2 + c*16 + 4);
      *(float4*)&r[8]  = ld4(sm + S_POOL2 + c*16 + 8);
      *(float4*)&r[12] = ld4(sm + S_POOL2 + c*16 + 12);
      float4 wq = ld4(&w3[co*192 + c*4]);
#pragma unroll
      for (int p = 0; p < 9; ++p) {
        int pyy = p / 3, pxx = p % 3;
        acc[p] += r[pyy*4+pxx]*wq.x + r[pyy*4+pxx+1]*wq.y
                + r[(pyy+1)*4+pxx]*wq.z + r[(pyy+1)*4+pxx+1]*wq.w;
      }
    }
#pragma unroll
    for (int p = 0; p < 9; ++p) {
      acc[p] += __shfl_xor(acc[p], 1, 64);
      acc[p] += __shfl_xor(acc[p], 2, 64);
    }
    if (c4 == 0) {
      float bb = b3[co], aa = a3[co];
#pragma unroll
      for (int p = 0; p < 9; ++p) sm[S_FEAT + co*9 + p] = prelu_f(acc[p] + bb, aa);
    }
  }
  __syncthreads();

  // ---- Phase G: lin4 (576->128) + prelu, coalesced w4 rows + wave reduce ----
  {
    int wv = tid >> 6, lane = tid & 63;
    for (int f = wv; f < 128; f += 4) {
      const float* wr = w4 + f*576;
      float acc = 0.f;
#pragma unroll
      for (int i = 0; i < 9; ++i) {
        int j = i*64 + lane;
        acc += wr[j] * sm[S_FEAT + j];
      }
#pragma unroll
      for (int off = 1; off < 64; off <<= 1) acc += __shfl_xor(acc, off, 64);
      if (lane == 0) sm[S_VEC + f] = prelu_f(acc + b4[f], a4[f]);
    }
  }
  __syncthreads();

  // ---- Phase H: lin5a (softmax) + lin5b (reg) + box regression ----
  if (tid < 6) {
    const float* wr = (tid < 2) ? (w5a + tid*128) : (w5b + (tid-2)*128);
    float acc = 0.f;
#pragma unroll
    for (int j = 0; j < 32; ++j) {
      float4 xv = ld4(sm + S_VEC + j*4);
      float4 wv = ld4(wr + j*4);
      acc += xv.x*wv.x + xv.y*wv.y + xv.z*wv.z + xv.w*wv.w;
    }
    acc += (tid < 2) ? b5a[tid] : b5b[tid-2];
    sm[S_LOUT + tid] = acc;
  }
  __syncthreads();
  if (tid == 0) {
    float l0 = sm[S_LOUT+0], l1 = sm[S_LOUT+1];
    float m = fmaxf(l0, l1);
    float e0 = expf(l0 - m), e1 = expf(l1 - m);
    float sc = e1 / (e0 + e1);
    float4 bb = ld4(&bboxes[n*4]);
    float bw = bb.z - bb.x, bh = bb.w - bb.y;
    float4 ob = make_float4(bb.x + sm[S_LOUT+2]*bw, bb.y + sm[S_LOUT+3]*bh,
                            bb.z + sm[S_LOUT+4]*bw, bb.w + sm[S_LOUT+5]*bh);
    *(float4*)&boxes[n*4] = ob;
    scores[n] = sc;
  }
}

// ---- sort by (-score, idx) via bitonic on packed keys; compact valid count ----
__global__ __launch_bounds__(1024) void sort_kernel(const float* __restrict__ scores,
                                                    const float* __restrict__ boxes,
                                                    int* __restrict__ order,
                                                    float* __restrict__ sboxes,
                                                    int* __restrict__ Vp) {
  __shared__ ull keys[NBOX];
  __shared__ int cnt;
  int tid = threadIdx.x;
  if (tid == 0) cnt = 0;
  __syncthreads();
  int local = 0;
  for (int i = tid; i < NBOX; i += 1024) {
    float s = scores[i];
    bool valid = (s >= 0.7f);
    unsigned hi = valid ? (0xFFFFFFFFu - __float_as_uint(s)) : 0xFFFFFFFFu;
    keys[i] = ((ull)hi << 32) | (unsigned)i;
    if (valid) local++;
  }
  atomicAdd(&cnt, local);
  __syncthreads();
  if (tid == 0) *Vp = cnt;
  for (int k = 2; k <= NBOX; k <<= 1) {
    for (int j = k >> 1; j > 0; j >>= 1) {
      __syncthreads();
      for (int i = tid; i < NBOX; i += 1024) {
        int ij = i ^ j;
        if (ij > i) {
          ull a = keys[i], b = keys[ij];
          bool up = ((i & k) == 0);
          if ((a > b) == up) { keys[i] = b; keys[ij] = a; }
        }
      }
    }
  }
  __syncthreads();
  for (int i = tid; i < NBOX; i += 1024) {
    int idx = (int)(unsigned)(keys[i] & 0xFFFFFFFFu);
    order[i] = idx;
    *(float4*)&sboxes[i*4] = *(const float4*)&boxes[idx*4];
  }
}

// ---- pairwise IoU suppression bitmask: row i, 64 words of bits j ----
__global__ __launch_bounds__(256) void iou_kernel(const float* __restrict__ sboxes,
                                                  const int* __restrict__ Vp,
                                                  ull* __restrict__ mask) {
  int i = blockIdx.x;
  int V = *Vp;
  if (i >= V) return;
  float4 bi = *(const float4*)&sboxes[i*4];
  float ai = fmaxf(bi.z - bi.x, 0.f) * fmaxf(bi.w - bi.y, 0.f);
  int lane = threadIdx.x & 63;
  for (int w = threadIdx.x >> 6; w < 64; w += 4) {
    int j = (w << 6) | lane;
    bool pred = false;
    if (j > i && j < V) {
      float4 bj = *(const float4*)&sboxes[j*4];
      float aj = fmaxf(bj.z - bj.x, 0.f) * fmaxf(bj.w - bj.y, 0.f);
      float xx1 = fmaxf(bi.x, bj.x), yy1 = fmaxf(bi.y, bj.y);
      float xx2 = fminf(bi.z, bj.z), yy2 = fminf(bi.w, bj.w);
      float inter = fmaxf(xx2 - xx1, 0.f) * fmaxf(yy2 - yy1, 0.f);
      float den = fmaxf(ai + aj - inter, 1e-12f);
      pred = (inter / den) > 0.5f;
    }
    ull bits = __ballot(pred);
    if (lane == 0) mask[(size_t)i*64 + w] = bits;
  }
}

// ---- serial greedy NMS scan (single wave, register suppression words) ----
#define CHUNK 16
__global__ __launch_bounds__(64) void nms_scan(const ull* __restrict__ mask,
                                               const int* __restrict__ Vp,
                                               const int* __restrict__ order,
                                               int* __restrict__ keep) {
  int lane = threadIdx.x;
  for (int idx = lane; idx < NBOX; idx += 64) keep[idx] = 0;
  __syncthreads();
  int V = *Vp;
  ull remw = 0;
  __shared__ ull buf[CHUNK][64];
  for (int base = 0; base < V; base += CHUNK) {
    int nn = min(CHUNK, V - base);
#pragma unroll
    for (int r = 0; r < CHUNK; ++r)
      if (r < nn) buf[r][lane] = mask[(size_t)(base + r)*64 + lane];
    for (int r = 0; r < nn; ++r) {
      int i = base + r;
      ull w = __shfl(remw, i >> 6, 64);
      if (!((w >> (i & 63)) & 1ull)) {
        remw |= buf[r][lane];
        if (lane == 0) keep[order[i]] = 1;
      }
    }
  }
}

__global__ __launch_bounds__(256) void out_kernel(const float* __restrict__ boxes,
                                                  const int* __restrict__ keep,
                                                  float* __restrict__ out) {
  int n = blockIdx.x * 256 + threadIdx.x;
  float4 b = *(const float4*)&boxes[n*4];
  float4 z = make_float4(0.f, 0.f, 0.f, 0.f);
  *(float4*)&out[n*4] = keep[n] ? b : z;
}

extern "C" void kernel_launch(void* const* d_in, const int* in_sizes, int n_in,
                              void* d_out, int out_size, void* d_ws, size_t ws_size,
                              hipStream_t stream) {
  const float* image  = (const float*)d_in[0];
  const float* bboxes = (const float*)d_in[1];
  const float* w1  = (const float*)d_in[2];
  const float* b1  = (const float*)d_in[3];
  const float* a1  = (const float*)d_in[4];
  const float* w2  = (const float*)d_in[5];
  const float* b2  = (const float*)d_in[6];
  const float* a2  = (const float*)d_in[7];
  const float* w3  = (const float*)d_in[8];
  const float* b3  = (const float*)d_in[9];
  const float* a3  = (const float*)d_in[10];
  const float* w4  = (const float*)d_in[11];
  const float* b4  = (const float*)d_in[12];
  const float* a4  = (const float*)d_in[13];
  const float* w5a = (const float*)d_in[14];
  const float* b5a = (const float*)d_in[15];
  const float* w5b = (const float*)d_in[16];
  const float* b5b = (const float*)d_in[17];

  char* ws = (char*)d_ws;
  float* boxes  = (float*)(ws + 0);        // 4096*4 f32
  float* scores = (float*)(ws + 65536);    // 4096 f32
  float* sboxes = (float*)(ws + 81920);    // 4096*4 f32 (sorted)
  int*   order  = (int*)  (ws + 147456);   // 4096 i32
  int*   Vp     = (int*)  (ws + 163840);   // 1 i32
  int*   keep   = (int*)  (ws + 163856);   // 4096 i32
  ull*   mask   = (ull*)  (ws + 180240);   // 4096*64 u64

  float* out = (float*)d_out;

  cnn_kernel<<<NBOX, 256, 0, stream>>>(image, bboxes, w1,b1,a1, w2,b2,a2, w3,b3,a3,
                                       w4,b4,a4, w5a,b5a, w5b,b5b, boxes, scores);
  sort_kernel<<<1, 1024, 0, stream>>>(scores, boxes, order, sboxes, Vp);
  iou_kernel<<<NBOX, 256, 0, stream>>>(sboxes, Vp, mask);
  nms_scan<<<1, 64, 0, stream>>>(mask, Vp, order, keep);
  out_kernel<<<16, 256, 0, stream>>>(boxes, keep, out);
}

// Round 7
// 538.373 us; speedup vs baseline: 1.0675x; 1.0675x over previous
//
#include <hip/hip_runtime.h>

typedef unsigned long long ull;

#define W_IMG 1920
#define H_IMG 1080
#define NBOX 4096

// ---- LDS layout (float offsets), total 9432 floats = 37728 B -> 4 blocks/CU ----
// conv1 phase: crop[3][24][28]=2016 | wt1[27][32]=864          | pool1[28][11][12]=3696
// conv2 phase: wt2[126][24]=3024 | buf2[24][81]=1944 | pool2[48][16]=768 | pool1 (live)
// head phase:  feat[576] | vec[128] | lout[6]   (reuse dead front region)
#define S_CROP  0
#define S_WT1   2016
#define S_WT2   0
#define S_BUF2  3024
#define S_POOL2 4968
#define S_POOL1 5736
#define S_FEAT  0
#define S_VEC   576
#define S_LOUT  704
#define SMEM_F  9432

__device__ __forceinline__ float4 ld4(const float* p) { return *(const float4*)p; }
__device__ __forceinline__ float prelu_f(float v, float a) { return v > 0.f ? v : a * v; }

// conv1(3x3,3->28) + maxpool(3,2,pad1) fused: one pooled output x 4 co per task.
// Raw conv max accumulated; bias+prelu applied after (monotone => bitwise-equal).
template<int SHIFT, int PMIN>
__device__ __forceinline__ void conv1_pool_task(const float* sm, int cq, int y0, int a0,
                                                float* mx) {
#pragma unroll
  for (int wy = 0; wy < 3; ++wy) {
    int y = y0 + wy;                 // conv output row, max 21
    if (y < 0) continue;             // pool top padding
    float acc0[3] = {0.f,0.f,0.f}, acc1[3] = {0.f,0.f,0.f};
    float acc2[3] = {0.f,0.f,0.f}, acc3[3] = {0.f,0.f,0.f};
#pragma unroll
    for (int c = 0; c < 3; ++c) {
#pragma unroll
      for (int kyy = 0; kyy < 3; ++kyy) {
        float r[8];
        const float* src = sm + S_CROP + c*672 + (y + kyy)*28 + a0;
        *(float4*)&r[0] = ld4(src);
        *(float4*)&r[4] = ld4(src + 4);
#pragma unroll
        for (int kxx = 0; kxx < 3; ++kxx) {
          float4 wq = ld4(sm + S_WT1 + (c*9 + kyy*3 + kxx)*32 + cq*4);
#pragma unroll
          for (int wx = PMIN; wx < 3; ++wx) {
            float v = r[SHIFT + wx + kxx];
            acc0[wx] += v*wq.x; acc1[wx] += v*wq.y;
            acc2[wx] += v*wq.z; acc3[wx] += v*wq.w;
          }
        }
      }
    }
#pragma unroll
    for (int wx = PMIN; wx < 3; ++wx) {
      mx[0] = fmaxf(mx[0], acc0[wx]);
      mx[1] = fmaxf(mx[1], acc1[wx]);
      mx[2] = fmaxf(mx[2], acc2[wx]);
      mx[3] = fmaxf(mx[3], acc3[wx]);
    }
  }
}

__global__ __launch_bounds__(256, 4) void cnn_kernel(
    const float* __restrict__ image, const float* __restrict__ bboxes,
    const float* __restrict__ w1, const float* __restrict__ b1, const float* __restrict__ a1,
    const float* __restrict__ w2, const float* __restrict__ b2, const float* __restrict__ a2,
    const float* __restrict__ w3, const float* __restrict__ b3, const float* __restrict__ a3,
    const float* __restrict__ w4, const float* __restrict__ b4, const float* __restrict__ a4,
    const float* __restrict__ w5a, const float* __restrict__ b5a,
    const float* __restrict__ w5b, const float* __restrict__ b5b,
    float* __restrict__ boxes, float* __restrict__ scores)
{
  __shared__ float sm[SMEM_F];
  __shared__ int s_ix[24], s_iy[24];
  const int tid = threadIdx.x;
  const int n = blockIdx.x;
  const float lo = -__builtin_inff();

  // ---- Phase A: crop indices + conv1 weight transpose stage ----
  if (tid < 24) {
    int x1 = min(max((int)bboxes[n*4+0], 0), W_IMG);
    int x2 = min(max((int)bboxes[n*4+2], 0), W_IMG);
    s_ix[tid] = min(max(x1 + (tid*(x2-x1))/24, 0), W_IMG-1);
  } else if (tid >= 64 && tid < 88) {
    int j = tid - 64;
    int y1 = min(max((int)bboxes[n*4+1], 0), H_IMG);
    int y2 = min(max((int)bboxes[n*4+3], 0), H_IMG);
    s_iy[j] = min(max(y1 + (j*(y2-y1))/24, 0), H_IMG-1);
  }
  for (int d = tid; d < 756; d += 256) {
    int k = d / 28, co = d % 28;
    sm[S_WT1 + k*32 + co] = w1[co*27 + k];
  }
  __syncthreads();
  // ---- crop + normalize: crop[c][y][x], row stride 28 ----
  for (int e = tid; e < 1728; e += 256) {
    int c = e / 576, rr = e % 576, y = rr / 24, x = rr % 24;
    float v = image[(s_iy[y]*W_IMG + s_ix[x])*3 + c];
    sm[S_CROP + c*672 + y*28 + x] = (v - 127.5f) * 0.0078125f;
  }
  __syncthreads();

  // ---- Phase B: conv1+pool fused, WAVE-UNIFORM px-class scheduling ----
  // 16 wave-slots: 0..6 odd px (SHIFT=1), 7..13 even px>=2 (SHIFT=3), 14..15 px=0 (SHIFT=-1).
  // Each wave runs 4 slots; class branch is wave-uniform (no intra-wave divergence).
  {
    const int wv = tid >> 6, lane = tid & 63;
#pragma unroll 1
    for (int k = 0; k < 4; ++k) {
      const int s = 4*k + wv;          // wave-uniform slot 0..15
      float mx[4] = {lo, lo, lo, lo};
      int cq, py, px;
      bool valid;
      if (s < 7) {                     // odd px: x0 = 2px-1 == 1 mod 4
        int idx = s*64 + lane;
        valid = idx < 385;
        cq = idx % 7; int q = idx / 7; if (q > 54) q = 54;
        py = q / 5; px = 2*(q % 5) + 1;
        conv1_pool_task<1,0>(sm, cq, 2*py - 1, (2*px - 1) & ~3, mx);
      } else if (s < 14) {             // even px>=2: x0 == 3 mod 4
        int idx = (s - 7)*64 + lane;
        valid = idx < 385;
        cq = idx % 7; int q = idx / 7; if (q > 54) q = 54;
        py = q / 5; px = 2*(q % 5) + 2;
        conv1_pool_task<3,0>(sm, cq, 2*py - 1, (2*px - 1) & ~3, mx);
      } else {                         // px == 0 (left edge)
        int idx = (s - 14)*64 + lane;
        valid = idx < 77;
        cq = idx % 7; py = idx / 7; if (py > 10) py = 10;
        px = 0;
        conv1_pool_task<-1,1>(sm, cq, 2*py - 1, 0, mx);
      }
      if (valid) {
        float4 bq = ld4(&b1[cq*4]);
        float4 aq = ld4(&a1[cq*4]);
        sm[S_POOL1 + (cq*4+0)*132 + py*12 + px] = prelu_f(mx[0] + bq.x, aq.x);
        sm[S_POOL1 + (cq*4+1)*132 + py*12 + px] = prelu_f(mx[1] + bq.y, aq.y);
        sm[S_POOL1 + (cq*4+2)*132 + py*12 + px] = prelu_f(mx[2] + bq.z, aq.z);
        sm[S_POOL1 + (cq*4+3)*132 + py*12 + px] = prelu_f(mx[3] + bq.w, aq.w);
      }
    }
  }
  __syncthreads();

  // ---- Phase D: conv2, 216 active threads, SINGLE code path.
  //      thread = (xh 0..1 [wave pair], ks 0..1, y 0..8, cqL 0..5).
  //      xh splits 9 cols as 0..4 / 4..8 (col 4 overlap-computed, written once);
  //      X0 = xh*4 is a wave-uniform ADDRESS, not a template param -> one body. ----
  {
    const int xh  = tid >> 7;
    const int hid = tid & 127;
    const int ks  = hid & 1;
    const int r2  = hid >> 1;          // 0..63
    const int cy  = r2 % 9, cqL = r2 / 9;
    const bool act = (r2 < 54);
    const int X0 = xh * 4;             // wave-uniform col base (0 or 4)
    for (int ch = 0; ch < 2; ++ch) {
      float acc0[5]={}, acc1[5]={}, acc2[5]={}, acc3[5]={};
#pragma unroll 1
      for (int h = 0; h < 2; ++h) {
        // stage wt2 K-half h (channels h*14..h*14+13), transposed [126 k][24 co]
        for (int d = tid; d < 1512; d += 256) {
          int co = d / 63, j = d % 63;
          float2 v = *(const float2*)&w2[(ch*24 + co)*252 + h*126 + 2*j];
          sm[S_WT2 + (2*j  )*24 + co] = v.x;
          sm[S_WT2 + (2*j+1)*24 + co] = v.y;
        }
        __syncthreads();
        if (act) {
#pragma unroll 1
          for (int cc = 0; cc < 7; ++cc) {
            int cl = ks*7 + cc;          // k-index within staged half
            int c  = h*14 + cl;          // global input channel
#pragma unroll
            for (int ky = 0; ky < 3; ++ky) {
              float rw[8];
              const float* src = sm + S_POOL1 + c*132 + (cy + ky)*12 + X0;
              *(float4*)&rw[0] = ld4(src);
              *(float4*)&rw[4] = ld4(src + 4);
#pragma unroll
              for (int kx = 0; kx < 3; ++kx) {
                float4 wq = ld4(sm + S_WT2 + ((cl*3 + ky)*3 + kx)*24 + cqL*4);
#pragma unroll
                for (int p = 0; p < 5; ++p) {
                  float v = rw[p + kx];
                  acc0[p] += v*wq.x; acc1[p] += v*wq.y;
                  acc2[p] += v*wq.z; acc3[p] += v*wq.w;
                }
              }
            }
          }
        }
        __syncthreads();   // staged weights free for restage / buf2 write next
      }
      if (act) {
#pragma unroll
        for (int p = 0; p < 5; ++p) {
          acc0[p] += __shfl_xor(acc0[p], 1, 64);
          acc1[p] += __shfl_xor(acc1[p], 1, 64);
          acc2[p] += __shfl_xor(acc2[p], 1, 64);
          acc3[p] += __shfl_xor(acc3[p], 1, 64);
        }
        if (ks == 0) {
          float4 bq = ld4(b2 + ch*24 + cqL*4);
          float4 aq = ld4(a2 + ch*24 + cqL*4);
          const int plo = xh;            // xh=1 skips overlapped col 4 (p=0)
#pragma unroll
          for (int p = 0; p < 5; ++p) {
            if (p >= plo) {
              sm[S_BUF2 + (cqL*4+0)*81 + cy*9 + X0 + p] = prelu_f(acc0[p] + bq.x, aq.x);
              sm[S_BUF2 + (cqL*4+1)*81 + cy*9 + X0 + p] = prelu_f(acc1[p] + bq.y, aq.y);
              sm[S_BUF2 + (cqL*4+2)*81 + cy*9 + X0 + p] = prelu_f(acc2[p] + bq.z, aq.z);
              sm[S_BUF2 + (cqL*4+3)*81 + cy*9 + X0 + p] = prelu_f(acc3[p] + bq.w, aq.w);
            }
          }
        }
      }
      __syncthreads();
      for (int o = tid; o < 384; o += 256) {           // pool2 (3,2,pad0) for this chunk
        int cl = o / 16, rem = o % 16, pyy = rem / 4, pxx = rem % 4;
        float m = lo;
#pragma unroll
        for (int ky = 0; ky < 3; ++ky)
#pragma unroll
          for (int kx = 0; kx < 3; ++kx)
            m = fmaxf(m, sm[S_BUF2 + cl*81 + (2*pyy+ky)*9 + (2*pxx+kx)]);
        sm[S_POOL2 + (ch*24 + cl)*16 + rem] = m;
      }
      __syncthreads();
    }
  }

  // ---- Phase F: conv3 (2x2, 48->64) -> feat[576] ----
  {
    int co = tid >> 2, c4 = tid & 3;
    float acc[9] = {};
    for (int cc = 0; cc < 12; ++cc) {
      int c = c4*12 + cc;
      float r[16];
      *(float4*)&r[0]  = ld4(sm + S_POOL2 + c*16);
      *(float4*)&r[4]  = ld4(sm + S_POOL2 + c*16 + 4);
      *(float4*)&r[8]  = ld4(sm + S_POOL2 + c*16 + 8);
      *(float4*)&r[12] = ld4(sm + S_POOL2 + c*16 + 12);
      float4 wq = ld4(&w3[co*192 + c*4]);
#pragma unroll
      for (int p = 0; p < 9; ++p) {
        int pyy = p / 3, pxx = p % 3;
        acc[p] += r[pyy*4+pxx]*wq.x + r[pyy*4+pxx+1]*wq.y
                + r[(pyy+1)*4+pxx]*wq.z + r[(pyy+1)*4+pxx+1]*wq.w;
      }
    }
#pragma unroll
    for (int p = 0; p < 9; ++p) {
      acc[p] += __shfl_xor(acc[p], 1, 64);
      acc[p] += __shfl_xor(acc[p], 2, 64);
    }
    if (c4 == 0) {
      float bb = b3[co], aa = a3[co];
#pragma unroll
      for (int p = 0; p < 9; ++p) sm[S_FEAT + co*9 + p] = prelu_f(acc[p] + bb, aa);
    }
  }
  __syncthreads();

  // ---- Phase G: lin4 (576->128) + prelu, coalesced w4 rows + wave reduce ----
  {
    int wv = tid >> 6, lane = tid & 63;
    for (int f = wv; f < 128; f += 4) {
      const float* wr = w4 + f*576;
      float acc = 0.f;
#pragma unroll
      for (int i = 0; i < 9; ++i) {
        int j = i*64 + lane;
        acc += wr[j] * sm[S_FEAT + j];
      }
#pragma unroll
      for (int off = 1; off < 64; off <<= 1) acc += __shfl_xor(acc, off, 64);
      if (lane == 0) sm[S_VEC + f] = prelu_f(acc + b4[f], a4[f]);
    }
  }
  __syncthreads();

  // ---- Phase H: lin5a (softmax) + lin5b (reg) + box regression ----
  if (tid < 6) {
    const float* wr = (tid < 2) ? (w5a + tid*128) : (w5b + (tid-2)*128);
    float acc = 0.f;
#pragma unroll
    for (int j = 0; j < 32; ++j) {
      float4 xv = ld4(sm + S_VEC + j*4);
      float4 wv = ld4(wr + j*4);
      acc += xv.x*wv.x + xv.y*wv.y + xv.z*wv.z + xv.w*wv.w;
    }
    acc += (tid < 2) ? b5a[tid] : b5b[tid-2];
    sm[S_LOUT + tid] = acc;
  }
  __syncthreads();
  if (tid == 0) {
    float l0 = sm[S_LOUT+0], l1 = sm[S_LOUT+1];
    float m = fmaxf(l0, l1);
    float e0 = expf(l0 - m), e1 = expf(l1 - m);
    float sc = e1 / (e0 + e1);
    float4 bb = ld4(&bboxes[n*4]);
    float bw = bb.z - bb.x, bh = bb.w - bb.y;
    float4 ob = make_float4(bb.x + sm[S_LOUT+2]*bw, bb.y + sm[S_LOUT+3]*bh,
                            bb.z + sm[S_LOUT+4]*bw, bb.w + sm[S_LOUT+5]*bh);
    *(float4*)&boxes[n*4] = ob;
    scores[n] = sc;
  }
}

// ---- sort by (-score, idx) via bitonic on packed keys; compact valid count ----
__global__ __launch_bounds__(1024) void sort_kernel(const float* __restrict__ scores,
                                                    const float* __restrict__ boxes,
                                                    int* __restrict__ order,
                                                    float* __restrict__ sboxes,
                                                    int* __restrict__ Vp) {
  __shared__ ull keys[NBOX];
  __shared__ int cnt;
  int tid = threadIdx.x;
  if (tid == 0) cnt = 0;
  __syncthreads();
  int local = 0;
  for (int i = tid; i < NBOX; i += 1024) {
    float s = scores[i];
    bool valid = (s >= 0.7f);
    unsigned hi = valid ? (0xFFFFFFFFu - __float_as_uint(s)) : 0xFFFFFFFFu;
    keys[i] = ((ull)hi << 32) | (unsigned)i;
    if (valid) local++;
  }
  atomicAdd(&cnt, local);
  __syncthreads();
  if (tid == 0) *Vp = cnt;
  for (int k = 2; k <= NBOX; k <<= 1) {
    for (int j = k >> 1; j > 0; j >>= 1) {
      __syncthreads();
      for (int i = tid; i < NBOX; i += 1024) {
        int ij = i ^ j;
        if (ij > i) {
          ull a = keys[i], b = keys[ij];
          bool up = ((i & k) == 0);
          if ((a > b) == up) { keys[i] = b; keys[ij] = a; }
        }
      }
    }
  }
  __syncthreads();
  for (int i = tid; i < NBOX; i += 1024) {
    int idx = (int)(unsigned)(keys[i] & 0xFFFFFFFFu);
    order[i] = idx;
    *(float4*)&sboxes[i*4] = *(const float4*)&boxes[idx*4];
  }
}

// ---- pairwise IoU suppression bitmask: row i, 64 words of bits j ----
__global__ __launch_bounds__(256) void iou_kernel(const float* __restrict__ sboxes,
                                                  const int* __restrict__ Vp,
                                                  ull* __restrict__ mask) {
  int i = blockIdx.x;
  int V = *Vp;
  if (i >= V) return;
  float4 bi = *(const float4*)&sboxes[i*4];
  float ai = fmaxf(bi.z - bi.x, 0.f) * fmaxf(bi.w - bi.y, 0.f);
  int lane = threadIdx.x & 63;
  for (int w = threadIdx.x >> 6; w < 64; w += 4) {
    int j = (w << 6) | lane;
    bool pred = false;
    if (j > i && j < V) {
      float4 bj = *(const float4*)&sboxes[j*4];
      float aj = fmaxf(bj.z - bj.x, 0.f) * fmaxf(bj.w - bj.y, 0.f);
      float xx1 = fmaxf(bi.x, bj.x), yy1 = fmaxf(bi.y, bj.y);
      float xx2 = fminf(bi.z, bj.z), yy2 = fminf(bi.w, bj.w);
      float inter = fmaxf(xx2 - xx1, 0.f) * fmaxf(yy2 - yy1, 0.f);
      float den = fmaxf(ai + aj - inter, 1e-12f);
      pred = (inter / den) > 0.5f;
    }
    ull bits = __ballot(pred);
    if (lane == 0) mask[(size_t)i*64 + w] = bits;
  }
}

// ---- serial greedy NMS scan (single wave, register suppression words) ----
#define CHUNK 16
__global__ __launch_bounds__(64) void nms_scan(const ull* __restrict__ mask,
                                               const int* __restrict__ Vp,
                                               const int* __restrict__ order,
                                               int* __restrict__ keep) {
  int lane = threadIdx.x;
  for (int idx = lane; idx < NBOX; idx += 64) keep[idx] = 0;
  __syncthreads();
  int V = *Vp;
  ull remw = 0;
  __shared__ ull buf[CHUNK][64];
  for (int base = 0; base < V; base += CHUNK) {
    int nn = min(CHUNK, V - base);
#pragma unroll
    for (int r = 0; r < CHUNK; ++r)
      if (r < nn) buf[r][lane] = mask[(size_t)(base + r)*64 + lane];
    for (int r = 0; r < nn; ++r) {
      int i = base + r;
      ull w = __shfl(remw, i >> 6, 64);
      if (!((w >> (i & 63)) & 1ull)) {
        remw |= buf[r][lane];
        if (lane == 0) keep[order[i]] = 1;
      }
    }
  }
}

__global__ __launch_bounds__(256) void out_kernel(const float* __restrict__ boxes,
                                                  const int* __restrict__ keep,
                                                  float* __restrict__ out) {
  int n = blockIdx.x * 256 + threadIdx.x;
  float4 b = *(const float4*)&boxes[n*4];
  float4 z = make_float4(0.f, 0.f, 0.f, 0.f);
  *(float4*)&out[n*4] = keep[n] ? b : z;
}

extern "C" void kernel_launch(void* const* d_in, const int* in_sizes, int n_in,
                              void* d_out, int out_size, void* d_ws, size_t ws_size,
                              hipStream_t stream) {
  const float* image  = (const float*)d_in[0];
  const float* bboxes = (const float*)d_in[1];
  const float* w1  = (const float*)d_in[2];
  const float* b1  = (const float*)d_in[3];
  const float* a1  = (const float*)d_in[4];
  const float* w2  = (const float*)d_in[5];
  const float* b2  = (const float*)d_in[6];
  const float* a2  = (const float*)d_in[7];
  const float* w3  = (const float*)d_in[8];
  const float* b3  = (const float*)d_in[9];
  const float* a3  = (const float*)d_in[10];
  const float* w4  = (const float*)d_in[11];
  const float* b4  = (const float*)d_in[12];
  const float* a4  = (const float*)d_in[13];
  const float* w5a = (const float*)d_in[14];
  const float* b5a = (const float*)d_in[15];
  const float* w5b = (const float*)d_in[16];
  const float* b5b = (const float*)d_in[17];

  char* ws = (char*)d_ws;
  float* boxes  = (float*)(ws + 0);        // 4096*4 f32
  float* scores = (float*)(ws + 65536);    // 4096 f32
  float* sboxes = (float*)(ws + 81920);    // 4096*4 f32 (sorted)
  int*   order  = (int*)  (ws + 147456);   // 4096 i32
  int*   Vp     = (int*)  (ws + 163840);   // 1 i32
  int*   keep   = (int*)  (ws + 163856);   // 4096 i32
  ull*   mask   = (ull*)  (ws + 180240);   // 4096*64 u64

  float* out = (float*)d_out;

  cnn_kernel<<<NBOX, 256, 0, stream>>>(image, bboxes, w1,b1,a1, w2,b2,a2, w3,b3,a3,
                                       w4,b4,a4, w5a,b5a, w5b,b5b, boxes, scores);
  sort_kernel<<<1, 1024, 0, stream>>>(scores, boxes, order, sboxes, Vp);
  iou_kernel<<<NBOX, 256, 0, stream>>>(sboxes, Vp, mask);
  nms_scan<<<1, 64, 0, stream>>>(mask, Vp, order, keep);
  out_kernel<<<16, 256, 0, stream>>>(boxes, keep, out);
}

// Round 8
// 410.243 us; speedup vs baseline: 1.4009x; 1.3123x over previous
//
#include <hip/hip_runtime.h>

typedef unsigned long long ull;
typedef __attribute__((ext_vector_type(8))) short bf16x8;
typedef __attribute__((ext_vector_type(4))) float f32x4;

#define W_IMG 1920
#define H_IMG 1080
#define NBOX 4096

// ---- LDS layout (float offsets), total 9432 floats = 37728 B -> 4 blocks/CU ----
// conv1 phase: crop[3][24][28]=2016 @0 | wt1[27][32]=864 @2016 | pool1 f32 [28][11][12]=3696 @5736
// convert:     pool1 -> bf16 planes [11][12][28] shorts x2 @ floats 0..3696 (crop/wt1 dead)
// conv2 MFMA:  planes (read) | buf2 [48][81]=3888 @3696 (overwrites dead pool1 f32)
// pool2:       [48][16]=768 @7584
// head:        feat[576]@0 | vec[128]@576 | lout[6]@704   (planes dead)
#define S_CROP  0
#define S_WT1   2016
#define S_POOL1 5736
#define S_BUF2  3696
#define S_POOL2 7584
#define S_FEAT  0
#define S_VEC   576
#define S_LOUT  704
#define SMEM_F  9432

#define WS_BT   2277392   // byte offset of bf16 weight planes in d_ws (2 planes x 13824 shorts)

__device__ __forceinline__ float4 ld4(const float* p) { return *(const float4*)p; }
__device__ __forceinline__ float prelu_f(float v, float a) { return v > 0.f ? v : a * v; }
__device__ __forceinline__ unsigned short bf16rn(float v) {
  unsigned u = __float_as_uint(v);
  return (unsigned short)((u + 0x7fffu + ((u >> 16) & 1u)) >> 16);
}
__device__ __forceinline__ float bf16tof(unsigned short h) {
  return __uint_as_float(((unsigned)h) << 16);
}

// ---- pre-kernel: w2 (48,28,3,3) f32 -> BT bf16 planes  bt[p][kk][co][c32] (c>=28 zero) ----
__global__ __launch_bounds__(256) void wconv_kernel(const float* __restrict__ w2,
                                                    unsigned short* __restrict__ bt) {
  int tid = threadIdx.x;
  for (int e = tid; e < 13824; e += 256) {     // e = (kk*48 + co)*32 + c
    int c = e & 31, rest = e >> 5;
    int co = rest % 48, kk = rest / 48;
    float v = (c < 28) ? w2[co*252 + c*9 + kk] : 0.f;
    unsigned short h1 = bf16rn(v);
    unsigned short h2 = bf16rn(v - bf16tof(h1));
    bt[e] = h1;
    bt[13824 + e] = h2;
  }
}

// conv1(3x3,3->28) + maxpool(3,2,pad1) fused: one pooled output x 4 co per task.
template<int SHIFT, int PMIN>
__device__ __forceinline__ void conv1_pool_task(const float* sm, int cq, int y0, int a0,
                                                float* mx) {
#pragma unroll
  for (int wy = 0; wy < 3; ++wy) {
    int y = y0 + wy;
    if (y < 0) continue;
    float acc0[3] = {0.f,0.f,0.f}, acc1[3] = {0.f,0.f,0.f};
    float acc2[3] = {0.f,0.f,0.f}, acc3[3] = {0.f,0.f,0.f};
#pragma unroll
    for (int c = 0; c < 3; ++c) {
#pragma unroll
      for (int kyy = 0; kyy < 3; ++kyy) {
        float r[8];
        const float* src = sm + S_CROP + c*672 + (y + kyy)*28 + a0;
        *(float4*)&r[0] = ld4(src);
        *(float4*)&r[4] = ld4(src + 4);
#pragma unroll
        for (int kxx = 0; kxx < 3; ++kxx) {
          float4 wq = ld4(sm + S_WT1 + (c*9 + kyy*3 + kxx)*32 + cq*4);
#pragma unroll
          for (int wx = PMIN; wx < 3; ++wx) {
            float v = r[SHIFT + wx + kxx];
            acc0[wx] += v*wq.x; acc1[wx] += v*wq.y;
            acc2[wx] += v*wq.z; acc3[wx] += v*wq.w;
          }
        }
      }
    }
#pragma unroll
    for (int wx = PMIN; wx < 3; ++wx) {
      mx[0] = fmaxf(mx[0], acc0[wx]);
      mx[1] = fmaxf(mx[1], acc1[wx]);
      mx[2] = fmaxf(mx[2], acc2[wx]);
      mx[3] = fmaxf(mx[3], acc3[wx]);
    }
  }
}

__global__ __launch_bounds__(256, 4) void cnn_kernel(
    const float* __restrict__ image, const float* __restrict__ bboxes,
    const float* __restrict__ w1, const float* __restrict__ b1, const float* __restrict__ a1,
    const unsigned short* __restrict__ wbt,
    const float* __restrict__ b2, const float* __restrict__ a2,
    const float* __restrict__ w3, const float* __restrict__ b3, const float* __restrict__ a3,
    const float* __restrict__ w4, const float* __restrict__ b4, const float* __restrict__ a4,
    const float* __restrict__ w5a, const float* __restrict__ b5a,
    const float* __restrict__ w5b, const float* __restrict__ b5b,
    float* __restrict__ boxes, float* __restrict__ scores)
{
  __shared__ float sm[SMEM_F];
  __shared__ int s_ix[24], s_iy[24];
  const int tid = threadIdx.x;
  const int n = blockIdx.x;
  const float lo = -__builtin_inff();

  // ---- Phase A: crop indices + conv1 weight transpose stage ----
  if (tid < 24) {
    int x1 = min(max((int)bboxes[n*4+0], 0), W_IMG);
    int x2 = min(max((int)bboxes[n*4+2], 0), W_IMG);
    s_ix[tid] = min(max(x1 + (tid*(x2-x1))/24, 0), W_IMG-1);
  } else if (tid >= 64 && tid < 88) {
    int j = tid - 64;
    int y1 = min(max((int)bboxes[n*4+1], 0), H_IMG);
    int y2 = min(max((int)bboxes[n*4+3], 0), H_IMG);
    s_iy[j] = min(max(y1 + (j*(y2-y1))/24, 0), H_IMG-1);
  }
  for (int d = tid; d < 756; d += 256) {
    int k = d / 28, co = d % 28;
    sm[S_WT1 + k*32 + co] = w1[co*27 + k];
  }
  __syncthreads();
  // ---- crop + normalize: crop[c][y][x], row stride 28 ----
  for (int e = tid; e < 1728; e += 256) {
    int c = e / 576, rr = e % 576, y = rr / 24, x = rr % 24;
    float v = image[(s_iy[y]*W_IMG + s_ix[x])*3 + c];
    sm[S_CROP + c*672 + y*28 + x] = (v - 127.5f) * 0.0078125f;
  }
  __syncthreads();

  // ---- Phase B: conv1+pool fused, WAVE-UNIFORM px-class scheduling ----
  {
    const int wv = tid >> 6, lane = tid & 63;
#pragma unroll 1
    for (int k = 0; k < 4; ++k) {
      const int s = 4*k + wv;
      float mx[4] = {lo, lo, lo, lo};
      int cq, py, px;
      bool valid;
      if (s < 7) {
        int idx = s*64 + lane;
        valid = idx < 385;
        cq = idx % 7; int q = idx / 7; if (q > 54) q = 54;
        py = q / 5; px = 2*(q % 5) + 1;
        conv1_pool_task<1,0>(sm, cq, 2*py - 1, (2*px - 1) & ~3, mx);
      } else if (s < 14) {
        int idx = (s - 7)*64 + lane;
        valid = idx < 385;
        cq = idx % 7; int q = idx / 7; if (q > 54) q = 54;
        py = q / 5; px = 2*(q % 5) + 2;
        conv1_pool_task<3,0>(sm, cq, 2*py - 1, (2*px - 1) & ~3, mx);
      } else {
        int idx = (s - 14)*64 + lane;
        valid = idx < 77;
        cq = idx % 7; py = idx / 7; if (py > 10) py = 10;
        px = 0;
        conv1_pool_task<-1,1>(sm, cq, 2*py - 1, 0, mx);
      }
      if (valid) {
        float4 bq = ld4(&b1[cq*4]);
        float4 aq = ld4(&a1[cq*4]);
        sm[S_POOL1 + (cq*4+0)*132 + py*12 + px] = prelu_f(mx[0] + bq.x, aq.x);
        sm[S_POOL1 + (cq*4+1)*132 + py*12 + px] = prelu_f(mx[1] + bq.y, aq.y);
        sm[S_POOL1 + (cq*4+2)*132 + py*12 + px] = prelu_f(mx[2] + bq.z, aq.z);
        sm[S_POOL1 + (cq*4+3)*132 + py*12 + px] = prelu_f(mx[3] + bq.w, aq.w);
      }
    }
  }
  __syncthreads();

  // ---- Phase C: pool1 f32 -> transposed bf16 planes [y][x][c] x2 (shorts @0 / @3696) ----
  {
    unsigned short* pl = (unsigned short*)sm;
    for (int e = tid; e < 3696; e += 256) {
      float v = sm[S_POOL1 + e];
      int c = e / 132, rem = e - c*132;       // rem = y*12+x
      int it = rem*28 + c;
      unsigned short h1 = bf16rn(v);
      pl[it] = h1;
      pl[3696 + it] = bf16rn(v - bf16tof(h1));
    }
  }
  __syncthreads();

  // ---- Phase D: conv2 via MFMA 16x16x32 bf16, 9 shifted GEMMs (ky,kx), K=32 (c pad, B zeros)
  //      C[96pad x 48] tiles: 6 Mtiles x 3 Ntiles = 18, wave w takes t%4==w. 3-term bf16 split. ----
  {
    const int wv = tid >> 6, lane = tid & 63;
    const int grp = lane >> 4, lr = lane & 15;
    const unsigned short* pl = (const unsigned short*)sm;
    const bf16x8* bt = (const bf16x8*)wbt;      // [2][9][48][4] bf16x8
#pragma unroll 1
    for (int t = wv; t < 18; t += 4) {
      const int mtile = t / 3, ntile = t - 3*(t/3);
      const int co = ntile*16 + lr;
      const int arow = min(mtile*16 + lr, 80);
      const int oy = (arow*57) >> 9;            // /9 for arow<256
      const int ox = arow - 9*oy;
      const int pixb = (oy*12 + ox)*28 + grp*8; // short idx base in plane
      f32x4 acc = {0.f, 0.f, 0.f, 0.f};
#pragma unroll
      for (int kk = 0; kk < 9; ++kk) {
        const int ky = kk / 3, kx = kk - 3*(kk/3);
        const int aoff = pixb + (ky*12 + kx)*28;
        union { bf16x8 v; ull d[2]; } A1, A2;
        A1.d[0] = *(const ull*)(pl + aoff);
        A1.d[1] = *(const ull*)(pl + aoff + 4);
        A2.d[0] = *(const ull*)(pl + 3696 + aoff);
        A2.d[1] = *(const ull*)(pl + 3696 + aoff + 4);
        const bf16x8 B1 = bt[(kk*48 + co)*4 + grp];
        const bf16x8 B2 = bt[1728 + (kk*48 + co)*4 + grp];
        acc = __builtin_amdgcn_mfma_f32_16x16x32_bf16(A1.v, B2, acc, 0, 0, 0);
        acc = __builtin_amdgcn_mfma_f32_16x16x32_bf16(A2.v, B1, acc, 0, 0, 0);
        acc = __builtin_amdgcn_mfma_f32_16x16x32_bf16(A1.v, B1, acc, 0, 0, 0);
      }
      const float bb = b2[co], aa = a2[co];
      const int p0 = mtile*16 + grp*4;
#pragma unroll
      for (int r = 0; r < 4; ++r) {
        int p = p0 + r;
        if (p < 81) sm[S_BUF2 + co*81 + p] = prelu_f(acc[r] + bb, aa);
      }
    }
  }
  __syncthreads();

  // ---- Phase E: pool2 (3,2,pad0) full 48 channels ----
  for (int o = tid; o < 768; o += 256) {
    int cl = o >> 4, rem = o & 15, pyy = rem >> 2, pxx = rem & 3;
    float m = lo;
#pragma unroll
    for (int ky = 0; ky < 3; ++ky)
#pragma unroll
      for (int kx = 0; kx < 3; ++kx)
        m = fmaxf(m, sm[S_BUF2 + cl*81 + (2*pyy+ky)*9 + (2*pxx+kx)]);
    sm[S_POOL2 + o] = m;
  }
  __syncthreads();

  // ---- Phase F: conv3 (2x2, 48->64) -> feat[576] ----
  {
    int co = tid >> 2, c4 = tid & 3;
    float acc[9] = {};
    for (int cc = 0; cc < 12; ++cc) {
      int c = c4*12 + cc;
      float r[16];
      *(float4*)&r[0]  = ld4(sm + S_POOL2 + c*16);
      *(float4*)&r[4]  = ld4(sm + S_POOL2 + c*16 + 4);
      *(float4*)&r[8]  = ld4(sm + S_POOL2 + c*16 + 8);
      *(float4*)&r[12] = ld4(sm + S_POOL2 + c*16 + 12);
      float4 wq = ld4(&w3[co*192 + c*4]);
#pragma unroll
      for (int p = 0; p < 9; ++p) {
        int pyy = p / 3, pxx = p % 3;
        acc[p] += r[pyy*4+pxx]*wq.x + r[pyy*4+pxx+1]*wq.y
                + r[(pyy+1)*4+pxx]*wq.z + r[(pyy+1)*4+pxx+1]*wq.w;
      }
    }
#pragma unroll
    for (int p = 0; p < 9; ++p) {
      acc[p] += __shfl_xor(acc[p], 1, 64);
      acc[p] += __shfl_xor(acc[p], 2, 64);
    }
    if (c4 == 0) {
      float bb = b3[co], aa = a3[co];
#pragma unroll
      for (int p = 0; p < 9; ++p) sm[S_FEAT + co*9 + p] = prelu_f(acc[p] + bb, aa);
    }
  }
  __syncthreads();

  // ---- Phase G: lin4 (576->128) + prelu ----
  {
    int wv = tid >> 6, lane = tid & 63;
    for (int f = wv; f < 128; f += 4) {
      const float* wr = w4 + f*576;
      float acc = 0.f;
#pragma unroll
      for (int i = 0; i < 9; ++i) {
        int j = i*64 + lane;
        acc += wr[j] * sm[S_FEAT + j];
      }
#pragma unroll
      for (int off = 1; off < 64; off <<= 1) acc += __shfl_xor(acc, off, 64);
      if (lane == 0) sm[S_VEC + f] = prelu_f(acc + b4[f], a4[f]);
    }
  }
  __syncthreads();

  // ---- Phase H: lin5a (softmax) + lin5b (reg) + box regression ----
  if (tid < 6) {
    const float* wr = (tid < 2) ? (w5a + tid*128) : (w5b + (tid-2)*128);
    float acc = 0.f;
#pragma unroll
    for (int j = 0; j < 32; ++j) {
      float4 xv = ld4(sm + S_VEC + j*4);
      float4 wv = ld4(wr + j*4);
      acc += xv.x*wv.x + xv.y*wv.y + xv.z*wv.z + xv.w*wv.w;
    }
    acc += (tid < 2) ? b5a[tid] : b5b[tid-2];
    sm[S_LOUT + tid] = acc;
  }
  __syncthreads();
  if (tid == 0) {
    float l0 = sm[S_LOUT+0], l1 = sm[S_LOUT+1];
    float m = fmaxf(l0, l1);
    float e0 = expf(l0 - m), e1 = expf(l1 - m);
    float sc = e1 / (e0 + e1);
    float4 bb = ld4(&bboxes[n*4]);
    float bw = bb.z - bb.x, bh = bb.w - bb.y;
    float4 ob = make_float4(bb.x + sm[S_LOUT+2]*bw, bb.y + sm[S_LOUT+3]*bh,
                            bb.z + sm[S_LOUT+4]*bw, bb.w + sm[S_LOUT+5]*bh);
    *(float4*)&boxes[n*4] = ob;
    scores[n] = sc;
  }
}

// ---- sort by (-score, idx) via bitonic; early-exit when no valid boxes ----
__global__ __launch_bounds__(1024) void sort_kernel(const float* __restrict__ scores,
                                                    const float* __restrict__ boxes,
                                                    int* __restrict__ order,
                                                    float* __restrict__ sboxes,
                                                    int* __restrict__ Vp) {
  __shared__ ull keys[NBOX];
  __shared__ int cnt;
  int tid = threadIdx.x;
  if (tid == 0) cnt = 0;
  __syncthreads();
  int local = 0;
  for (int i = tid; i < NBOX; i += 1024) {
    float s = scores[i];
    bool valid = (s >= 0.7f);
    unsigned hi = valid ? (0xFFFFFFFFu - __float_as_uint(s)) : 0xFFFFFFFFu;
    keys[i] = ((ull)hi << 32) | (unsigned)i;
    if (valid) local++;
  }
  atomicAdd(&cnt, local);
  __syncthreads();
  if (tid == 0) *Vp = cnt;
  if (cnt == 0) return;        // nothing valid: order/sboxes are never read downstream
  for (int k = 2; k <= NBOX; k <<= 1) {
    for (int j = k >> 1; j > 0; j >>= 1) {
      __syncthreads();
      for (int i = tid; i < NBOX; i += 1024) {
        int ij = i ^ j;
        if (ij > i) {
          ull a = keys[i], b = keys[ij];
          bool up = ((i & k) == 0);
          if ((a > b) == up) { keys[i] = b; keys[ij] = a; }
        }
      }
    }
  }
  __syncthreads();
  for (int i = tid; i < NBOX; i += 1024) {
    int idx = (int)(unsigned)(keys[i] & 0xFFFFFFFFu);
    order[i] = idx;
    *(float4*)&sboxes[i*4] = *(const float4*)&boxes[idx*4];
  }
}

// ---- pairwise IoU suppression bitmask ----
__global__ __launch_bounds__(256) void iou_kernel(const float* __restrict__ sboxes,
                                                  const int* __restrict__ Vp,
                                                  ull* __restrict__ mask) {
  int i = blockIdx.x;
  int V = *Vp;
  if (i >= V) return;
  float4 bi = *(const float4*)&sboxes[i*4];
  float ai = fmaxf(bi.z - bi.x, 0.f) * fmaxf(bi.w - bi.y, 0.f);
  int lane = threadIdx.x & 63;
  for (int w = threadIdx.x >> 6; w < 64; w += 4) {
    int j = (w << 6) | lane;
    bool pred = false;
    if (j > i && j < V) {
      float4 bj = *(const float4*)&sboxes[j*4];
      float aj = fmaxf(bj.z - bj.x, 0.f) * fmaxf(bj.w - bj.y, 0.f);
      float xx1 = fmaxf(bi.x, bj.x), yy1 = fmaxf(bi.y, bj.y);
      float xx2 = fminf(bi.z, bj.z), yy2 = fminf(bi.w, bj.w);
      float inter = fmaxf(xx2 - xx1, 0.f) * fmaxf(yy2 - yy1, 0.f);
      float den = fmaxf(ai + aj - inter, 1e-12f);
      pred = (inter / den) > 0.5f;
    }
    ull bits = __ballot(pred);
    if (lane == 0) mask[(size_t)i*64 + w] = bits;
  }
}

// ---- serial greedy NMS scan (single wave) ----
#define CHUNK 16
__global__ __launch_bounds__(64) void nms_scan(const ull* __restrict__ mask,
                                               const int* __restrict__ Vp,
                                               const int* __restrict__ order,
                                               int* __restrict__ keep) {
  int lane = threadIdx.x;
  for (int idx = lane; idx < NBOX; idx += 64) keep[idx] = 0;
  __syncthreads();
  int V = *Vp;
  ull remw = 0;
  __shared__ ull buf[CHUNK][64];
  for (int base = 0; base < V; base += CHUNK) {
    int nn = min(CHUNK, V - base);
#pragma unroll
    for (int r = 0; r < CHUNK; ++r)
      if (r < nn) buf[r][lane] = mask[(size_t)(base + r)*64 + lane];
    for (int r = 0; r < nn; ++r) {
      int i = base + r;
      ull w = __shfl(remw, i >> 6, 64);
      if (!((w >> (i & 63)) & 1ull)) {
        remw |= buf[r][lane];
        if (lane == 0) keep[order[i]] = 1;
      }
    }
  }
}

__global__ __launch_bounds__(256) void out_kernel(const float* __restrict__ boxes,
                                                  const int* __restrict__ keep,
                                                  float* __restrict__ out) {
  int n = blockIdx.x * 256 + threadIdx.x;
  float4 b = *(const float4*)&boxes[n*4];
  float4 z = make_float4(0.f, 0.f, 0.f, 0.f);
  *(float4*)&out[n*4] = keep[n] ? b : z;
}

extern "C" void kernel_launch(void* const* d_in, const int* in_sizes, int n_in,
                              void* d_out, int out_size, void* d_ws, size_t ws_size,
                              hipStream_t stream) {
  const float* image  = (const float*)d_in[0];
  const float* bboxes = (const float*)d_in[1];
  const float* w1  = (const float*)d_in[2];
  const float* b1  = (const float*)d_in[3];
  const float* a1  = (const float*)d_in[4];
  const float* w2  = (const float*)d_in[5];
  const float* b2  = (const float*)d_in[6];
  const float* a2  = (const float*)d_in[7];
  const float* w3  = (const float*)d_in[8];
  const float* b3  = (const float*)d_in[9];
  const float* a3  = (const float*)d_in[10];
  const float* w4  = (const float*)d_in[11];
  const float* b4  = (const float*)d_in[12];
  const float* a4  = (const float*)d_in[13];
  const float* w5a = (const float*)d_in[14];
  const float* b5a = (const float*)d_in[15];
  const float* w5b = (const float*)d_in[16];
  const float* b5b = (const float*)d_in[17];

  char* ws = (char*)d_ws;
  float* boxes  = (float*)(ws + 0);        // 4096*4 f32
  float* scores = (float*)(ws + 65536);    // 4096 f32
  float* sboxes = (float*)(ws + 81920);    // 4096*4 f32 (sorted)
  int*   order  = (int*)  (ws + 147456);   // 4096 i32
  int*   Vp     = (int*)  (ws + 163840);   // 1 i32
  int*   keep   = (int*)  (ws + 163856);   // 4096 i32
  ull*   mask   = (ull*)  (ws + 180240);   // 4096*64 u64 -> ends 2277392
  unsigned short* wbt = (unsigned short*)(ws + WS_BT); // 2*13824 shorts = 55296 B

  float* out = (float*)d_out;

  wconv_kernel<<<1, 256, 0, stream>>>(w2, wbt);
  cnn_kernel<<<NBOX, 256, 0, stream>>>(image, bboxes, w1,b1,a1, wbt, b2,a2, w3,b3,a3,
                                       w4,b4,a4, w5a,b5a, w5b,b5b, boxes, scores);
  sort_kernel<<<1, 1024, 0, stream>>>(scores, boxes, order, sboxes, Vp);
  iou_kernel<<<NBOX, 256, 0, stream>>>(sboxes, Vp, mask);
  nms_scan<<<1, 64, 0, stream>>>(mask, Vp, order, keep);
  out_kernel<<<16, 256, 0, stream>>>(boxes, keep, out);
}

// Round 9
// 398.982 us; speedup vs baseline: 1.4405x; 1.0282x over previous
//
#include <hip/hip_runtime.h>

typedef unsigned long long ull;
typedef __attribute__((ext_vector_type(8))) short bf16x8;
typedef __attribute__((ext_vector_type(4))) float f32x4;

#define W_IMG 1920
#define H_IMG 1080
#define NBOX 4096

// ---- LDS layout (float offsets), total 8848 floats = 35392 B -> 4 blocks/CU ----
// crop f32 [3][24][28] = 2016                 @ [0, 2016)
// cbuf bf16 [28 co][224 pix pad] = 6272 sh    @ floats [2016, 5152)   (conv1 raw out, per chunk)
// planes bf16 2x[11][12][28] = 7392 sh        @ floats [5152, 8848)   (pool1 dual-plane, conv2 A)
// buf2 f32 [48][81] = 3888                    @ [0, 3888)     (crop+cbuf dead)
// pool2 f32 [48][16] = 768                    @ [3888, 4656)
// feat f32 [576] @ [0,576) | vec [576,704) | lout [704,710)   (planes dead)
#define S_CROP   0
#define S_CBUF   2016
#define S_PLANES 5152
#define S_BUF2   0
#define S_POOL2  3888
#define S_FEAT   0
#define S_VEC    576
#define S_LOUT   704
#define SMEM_F   8848

#define WS_BT    2277392  // w2 planes: 2 x 13824 shorts = 55296 B
#define WS_BT1   2332688  // w1 planes: 2048 shorts = 4096 B

__device__ __forceinline__ float4 ld4(const float* p) { return *(const float4*)p; }
__device__ __forceinline__ float prelu_f(float v, float a) { return v > 0.f ? v : a * v; }
__device__ __forceinline__ unsigned short bf16rn(float v) {
  unsigned u = __float_as_uint(v);
  return (unsigned short)((u + 0x7fffu + ((u >> 16) & 1u)) >> 16);
}
__device__ __forceinline__ float bf16tof(unsigned short h) {
  return __uint_as_float(((unsigned)h) << 16);
}

// ---- pre-kernel: weight bf16 dual-plane conversion (w2 -> bt, w1 -> bt1) ----
// bt  layout: [plane][kk(9)][co(48)][c(32)]   (c>=28 zero)
// bt1 layout: [plane][grp(4)][co(32)][j(8)]   (k=grp*8+j >=27 zero, co>=28 zero)
__global__ __launch_bounds__(256) void wconv_kernel(const float* __restrict__ w2,
                                                    const float* __restrict__ w1,
                                                    unsigned short* __restrict__ bt,
                                                    unsigned short* __restrict__ bt1) {
  int b = blockIdx.x, tid = threadIdx.x;
  if (b < 16) {
    for (int e = b*864 + tid; e < (b+1)*864; e += 256) {   // e = (kk*48+co)*32 + c
      int c = e & 31, rest = e >> 5;
      int co = rest % 48, kk = rest / 48;
      float v = (c < 28) ? w2[co*252 + c*9 + kk] : 0.f;
      unsigned short h1 = bf16rn(v);
      bt[e] = h1;
      bt[13824 + e] = bf16rn(v - bf16tof(h1));
    }
  } else {
    for (int e = tid; e < 2048; e += 256) {                // e = ((pl*4+grp)*32+co)*8 + j
      int j = e & 7, rest = e >> 3;
      int co = rest & 31, pg = rest >> 5;
      int grp = pg & 3, plane = pg >> 2;
      int k = grp*8 + j;
      float v = (k < 27 && co < 28) ? w1[co*27 + k] : 0.f;
      unsigned short h1 = bf16rn(v);
      bt1[e] = plane ? bf16rn(v - bf16tof(h1)) : h1;
    }
  }
}

__global__ __launch_bounds__(256, 4) void cnn_kernel(
    const float* __restrict__ image, const float* __restrict__ bboxes,
    const unsigned short* __restrict__ wbt1,
    const float* __restrict__ b1, const float* __restrict__ a1,
    const unsigned short* __restrict__ wbt,
    const float* __restrict__ b2, const float* __restrict__ a2,
    const float* __restrict__ w3, const float* __restrict__ b3, const float* __restrict__ a3,
    const float* __restrict__ w4, const float* __restrict__ b4, const float* __restrict__ a4,
    const float* __restrict__ w5a, const float* __restrict__ b5a,
    const float* __restrict__ w5b, const float* __restrict__ b5b,
    float* __restrict__ boxes, float* __restrict__ scores)
{
  __shared__ float sm[SMEM_F];
  __shared__ int s_ix[24], s_iy[24];
  const int tid = threadIdx.x;
  const int n = blockIdx.x;
  const float lo = -__builtin_inff();
  const int lane = tid & 63, wv = tid >> 6;
  const int grp = lane >> 4, lr = lane & 15;

  // ---- conv1 B-fragment preload: [plane][ntile] from global (16 VGPR) ----
  bf16x8 c1B[2][2];
  {
    const bf16x8* btc = (const bf16x8*)wbt1;      // [(pl*4+grp)*32 + co]
    c1B[0][0] = btc[(0*4 + grp)*32 + lr];
    c1B[0][1] = btc[(0*4 + grp)*32 + 16 + lr];
    c1B[1][0] = btc[(1*4 + grp)*32 + lr];
    c1B[1][1] = btc[(1*4 + grp)*32 + 16 + lr];
  }
  // per-lane A-build offsets: k = grp*8+j -> (c,ky,kx); off = c*672 + ky*28 + kx
  int aoff[8];
#pragma unroll
  for (int j = 0; j < 8; ++j) {
    int k = grp*8 + j;
    int c = k / 9, rr = k - 9*c, ky = rr / 3, kx = rr - 3*ky;
    aoff[j] = c*672 + ky*28 + kx;
  }

  // ---- Phase A: crop indices + crop/normalize staging ----
  if (tid < 24) {
    int x1 = min(max((int)bboxes[n*4+0], 0), W_IMG);
    int x2 = min(max((int)bboxes[n*4+2], 0), W_IMG);
    s_ix[tid] = min(max(x1 + (tid*(x2-x1))/24, 0), W_IMG-1);
  } else if (tid >= 64 && tid < 88) {
    int j = tid - 64;
    int y1 = min(max((int)bboxes[n*4+1], 0), H_IMG);
    int y2 = min(max((int)bboxes[n*4+3], 0), H_IMG);
    s_iy[j] = min(max(y1 + (j*(y2-y1))/24, 0), H_IMG-1);
  }
  __syncthreads();
  for (int e = tid; e < 1728; e += 256) {
    int c = e / 576, rr = e % 576, y = rr / 24, x = rr % 24;
    float v = image[(s_iy[y]*W_IMG + s_ix[x])*3 + c];
    sm[S_CROP + c*672 + y*28 + x] = (v - 127.5f) * 0.0078125f;
  }
  __syncthreads();

  // ---- Phase B: conv1 via MFMA (implicit im2col, K=27->32, N=28->32, bf16x3),
  //      3 row-chunks; cbuf bf16 [co][pix]; fused pool+prelu -> dual bf16 planes ----
  {
    unsigned short* cb = (unsigned short*)(sm + S_CBUF);
    unsigned short* pl = (unsigned short*)(sm + S_PLANES);
    const int c_r0[3] = {0, 7, 15};
    const int c_R [3] = {8, 9, 7};
    const int c_p0[3] = {0, 4, 8};
    const int c_np[3] = {4, 4, 3};
#pragma unroll 1
    for (int ck = 0; ck < 3; ++ck) {
      const int r0 = c_r0[ck], R = c_R[ck], p0 = c_p0[ck], np = c_np[ck];
      const int npix = R*22;
      const int mt = (npix + 15) >> 4;
#pragma unroll 1
      for (int t = wv; t < mt; t += 4) {
        int row = t*16 + lr;
        int pix = min(row, npix - 1);
        int ly = pix / 22;
        int x  = pix - ly*22;
        int base = (r0 + ly)*28 + x;       // S_CROP==0
        unsigned short h1[8], h2[8];
#pragma unroll
        for (int j = 0; j < 8; ++j) {
          float v = 0.f;
          if (grp*8 + j < 27) v = sm[base + aoff[j]];
          h1[j] = bf16rn(v);
          h2[j] = bf16rn(v - bf16tof(h1[j]));
        }
        union { bf16x8 v; unsigned u[4]; } A1, A2;
#pragma unroll
        for (int q = 0; q < 4; ++q) {
          A1.u[q] = (unsigned)h1[2*q] | ((unsigned)h1[2*q+1] << 16);
          A2.u[q] = (unsigned)h2[2*q] | ((unsigned)h2[2*q+1] << 16);
        }
        f32x4 acc0 = {0.f,0.f,0.f,0.f}, acc1 = {0.f,0.f,0.f,0.f};
        acc0 = __builtin_amdgcn_mfma_f32_16x16x32_bf16(A1.v, c1B[1][0], acc0, 0, 0, 0);
        acc0 = __builtin_amdgcn_mfma_f32_16x16x32_bf16(A2.v, c1B[0][0], acc0, 0, 0, 0);
        acc0 = __builtin_amdgcn_mfma_f32_16x16x32_bf16(A1.v, c1B[0][0], acc0, 0, 0, 0);
        acc1 = __builtin_amdgcn_mfma_f32_16x16x32_bf16(A1.v, c1B[1][1], acc1, 0, 0, 0);
        acc1 = __builtin_amdgcn_mfma_f32_16x16x32_bf16(A2.v, c1B[0][1], acc1, 0, 0, 0);
        acc1 = __builtin_amdgcn_mfma_f32_16x16x32_bf16(A1.v, c1B[0][1], acc1, 0, 0, 0);
        // C-write: col co = lr / 16+lr ; rows p0r..p0r+3 (consecutive pixels) -> b64
        int p0r = t*16 + grp*4;
        union { ull d; unsigned short s[4]; } W;
#pragma unroll
        for (int r = 0; r < 4; ++r) W.s[r] = bf16rn(acc0[r]);
        *(ull*)(cb + lr*224 + p0r) = W.d;
        if (lr < 12) {
#pragma unroll
          for (int r = 0; r < 4; ++r) W.s[r] = bf16rn(acc1[r]);
          *(ull*)(cb + (16 + lr)*224 + p0r) = W.d;
        }
      }
      __syncthreads();
      // pool(3,2,pad1) rows p0..p0+np-1 + bias + prelu -> dual bf16 planes [y][x][c]
      const int npt = np * 308;            // o = pyl*308 + co*11 + px
      for (int o = tid; o < npt; o += 256) {
        int pyl = o / 308, rem = o - pyl*308;
        int co = rem / 11, px = rem - co*11;
        int py = p0 + pyl;
        int rlo = max(2*py - 1, 0) - r0, rhi = 2*py + 1 - r0;
        int clo = max(2*px - 1, 0), chi = min(2*px + 1, 21);
        float m = lo;
        for (int r = rlo; r <= rhi; ++r)
          for (int c2 = clo; c2 <= chi; ++c2)
            m = fmaxf(m, bf16tof(cb[co*224 + r*22 + c2]));
        float v = prelu_f(m + b1[co], a1[co]);
        unsigned short g1 = bf16rn(v);
        int it = (py*12 + px)*28 + co;
        pl[it] = g1;
        pl[3696 + it] = bf16rn(v - bf16tof(g1));
      }
      __syncthreads();
    }
  }

  // ---- Phase D: conv2 via MFMA 16x16x32 bf16, 9 shifted GEMMs (ky,kx), K=32 pad ----
  {
    const unsigned short* pl = (const unsigned short*)(sm + S_PLANES);
    const bf16x8* bt = (const bf16x8*)wbt;      // [2][9][48][4] bf16x8
#pragma unroll 1
    for (int t = wv; t < 18; t += 4) {
      const int mtile = t / 3, ntile = t - 3*(t/3);
      const int co = ntile*16 + lr;
      const int arow = min(mtile*16 + lr, 80);
      const int oy = (arow*57) >> 9;
      const int ox = arow - 9*oy;
      const int pixb = (oy*12 + ox)*28 + grp*8;
      f32x4 acc = {0.f, 0.f, 0.f, 0.f};
#pragma unroll
      for (int kk = 0; kk < 9; ++kk) {
        const int ky = kk / 3, kx = kk - 3*(kk/3);
        const int aoff2 = pixb + (ky*12 + kx)*28;
        union { bf16x8 v; ull d[2]; } A1, A2;
        A1.d[0] = *(const ull*)(pl + aoff2);
        A1.d[1] = *(const ull*)(pl + aoff2 + 4);
        A2.d[0] = *(const ull*)(pl + 3696 + aoff2);
        A2.d[1] = *(const ull*)(pl + 3696 + aoff2 + 4);
        const bf16x8 B1 = bt[(kk*48 + co)*4 + grp];
        const bf16x8 B2 = bt[1728 + (kk*48 + co)*4 + grp];
        acc = __builtin_amdgcn_mfma_f32_16x16x32_bf16(A1.v, B2, acc, 0, 0, 0);
        acc = __builtin_amdgcn_mfma_f32_16x16x32_bf16(A2.v, B1, acc, 0, 0, 0);
        acc = __builtin_amdgcn_mfma_f32_16x16x32_bf16(A1.v, B1, acc, 0, 0, 0);
      }
      const float bb = b2[co], aa = a2[co];
      const int p0 = mtile*16 + grp*4;
#pragma unroll
      for (int r = 0; r < 4; ++r) {
        int p = p0 + r;
        if (p < 81) sm[S_BUF2 + co*81 + p] = prelu_f(acc[r] + bb, aa);
      }
    }
  }
  __syncthreads();

  // ---- Phase E: pool2 (3,2,pad0) full 48 channels ----
  for (int o = tid; o < 768; o += 256) {
    int cl = o >> 4, rem = o & 15, pyy = rem >> 2, pxx = rem & 3;
    float m = lo;
#pragma unroll
    for (int ky = 0; ky < 3; ++ky)
#pragma unroll
      for (int kx = 0; kx < 3; ++kx)
        m = fmaxf(m, sm[S_BUF2 + cl*81 + (2*pyy+ky)*9 + (2*pxx+kx)]);
    sm[S_POOL2 + o] = m;
  }
  __syncthreads();

  // ---- Phase F: conv3 (2x2, 48->64) -> feat[576] ----
  {
    int co = tid >> 2, c4 = tid & 3;
    float acc[9] = {};
    for (int cc = 0; cc < 12; ++cc) {
      int c = c4*12 + cc;
      float r[16];
      *(float4*)&r[0]  = ld4(sm + S_POOL2 + c*16);
      *(float4*)&r[4]  = ld4(sm + S_POOL2 + c*16 + 4);
      *(float4*)&r[8]  = ld4(sm + S_POOL2 + c*16 + 8);
      *(float4*)&r[12] = ld4(sm + S_POOL2 + c*16 + 12);
      float4 wq = ld4(&w3[co*192 + c*4]);
#pragma unroll
      for (int p = 0; p < 9; ++p) {
        int pyy = p / 3, pxx = p % 3;
        acc[p] += r[pyy*4+pxx]*wq.x + r[pyy*4+pxx+1]*wq.y
                + r[(pyy+1)*4+pxx]*wq.z + r[(pyy+1)*4+pxx+1]*wq.w;
      }
    }
#pragma unroll
    for (int p = 0; p < 9; ++p) {
      acc[p] += __shfl_xor(acc[p], 1, 64);
      acc[p] += __shfl_xor(acc[p], 2, 64);
    }
    if (c4 == 0) {
      float bb = b3[co], aa = a3[co];
#pragma unroll
      for (int p = 0; p < 9; ++p) sm[S_FEAT + co*9 + p] = prelu_f(acc[p] + bb, aa);
    }
  }
  __syncthreads();

  // ---- Phase G: lin4 (576->128) + prelu ----
  {
    for (int f = wv; f < 128; f += 4) {
      const float* wr = w4 + f*576;
      float acc = 0.f;
#pragma unroll
      for (int i = 0; i < 9; ++i) {
        int j = i*64 + lane;
        acc += wr[j] * sm[S_FEAT + j];
      }
#pragma unroll
      for (int off = 1; off < 64; off <<= 1) acc += __shfl_xor(acc, off, 64);
      if (lane == 0) sm[S_VEC + f] = prelu_f(acc + b4[f], a4[f]);
    }
  }
  __syncthreads();

  // ---- Phase H: lin5a (softmax) + lin5b (reg) + box regression ----
  if (tid < 6) {
    const float* wr = (tid < 2) ? (w5a + tid*128) : (w5b + (tid-2)*128);
    float acc = 0.f;
#pragma unroll
    for (int j = 0; j < 32; ++j) {
      float4 xv = ld4(sm + S_VEC + j*4);
      float4 wv = ld4(wr + j*4);
      acc += xv.x*wv.x + xv.y*wv.y + xv.z*wv.z + xv.w*wv.w;
    }
    acc += (tid < 2) ? b5a[tid] : b5b[tid-2];
    sm[S_LOUT + tid] = acc;
  }
  __syncthreads();
  if (tid == 0) {
    float l0 = sm[S_LOUT+0], l1 = sm[S_LOUT+1];
    float m = fmaxf(l0, l1);
    float e0 = expf(l0 - m), e1 = expf(l1 - m);
    float sc = e1 / (e0 + e1);
    float4 bb = ld4(&bboxes[n*4]);
    float bw = bb.z - bb.x, bh = bb.w - bb.y;
    float4 ob = make_float4(bb.x + sm[S_LOUT+2]*bw, bb.y + sm[S_LOUT+3]*bh,
                            bb.z + sm[S_LOUT+4]*bw, bb.w + sm[S_LOUT+5]*bh);
    *(float4*)&boxes[n*4] = ob;
    scores[n] = sc;
  }
}

// ---- sort by (-score, idx) via bitonic; early-exit when no valid boxes ----
__global__ __launch_bounds__(1024) void sort_kernel(const float* __restrict__ scores,
                                                    const float* __restrict__ boxes,
                                                    int* __restrict__ order,
                                                    float* __restrict__ sboxes,
                                                    int* __restrict__ Vp) {
  __shared__ ull keys[NBOX];
  __shared__ int cnt;
  int tid = threadIdx.x;
  if (tid == 0) cnt = 0;
  __syncthreads();
  int local = 0;
  for (int i = tid; i < NBOX; i += 1024) {
    float s = scores[i];
    bool valid = (s >= 0.7f);
    unsigned hi = valid ? (0xFFFFFFFFu - __float_as_uint(s)) : 0xFFFFFFFFu;
    keys[i] = ((ull)hi << 32) | (unsigned)i;
    if (valid) local++;
  }
  atomicAdd(&cnt, local);
  __syncthreads();
  if (tid == 0) *Vp = cnt;
  if (cnt == 0) return;
  for (int k = 2; k <= NBOX; k <<= 1) {
    for (int j = k >> 1; j > 0; j >>= 1) {
      __syncthreads();
      for (int i = tid; i < NBOX; i += 1024) {
        int ij = i ^ j;
        if (ij > i) {
          ull a = keys[i], b = keys[ij];
          bool up = ((i & k) == 0);
          if ((a > b) == up) { keys[i] = b; keys[ij] = a; }
        }
      }
    }
  }
  __syncthreads();
  for (int i = tid; i < NBOX; i += 1024) {
    int idx = (int)(unsigned)(keys[i] & 0xFFFFFFFFu);
    order[i] = idx;
    *(float4*)&sboxes[i*4] = *(const float4*)&boxes[idx*4];
  }
}

// ---- pairwise IoU suppression bitmask ----
__global__ __launch_bounds__(256) void iou_kernel(const float* __restrict__ sboxes,
                                                  const int* __restrict__ Vp,
                                                  ull* __restrict__ mask) {
  int i = blockIdx.x;
  int V = *Vp;
  if (i >= V) return;
  float4 bi = *(const float4*)&sboxes[i*4];
  float ai = fmaxf(bi.z - bi.x, 0.f) * fmaxf(bi.w - bi.y, 0.f);
  int lane = threadIdx.x & 63;
  for (int w = threadIdx.x >> 6; w < 64; w += 4) {
    int j = (w << 6) | lane;
    bool pred = false;
    if (j > i && j < V) {
      float4 bj = *(const float4*)&sboxes[j*4];
      float aj = fmaxf(bj.z - bj.x, 0.f) * fmaxf(bj.w - bj.y, 0.f);
      float xx1 = fmaxf(bi.x, bj.x), yy1 = fmaxf(bi.y, bj.y);
      float xx2 = fminf(bi.z, bj.z), yy2 = fminf(bi.w, bj.w);
      float inter = fmaxf(xx2 - xx1, 0.f) * fmaxf(yy2 - yy1, 0.f);
      float den = fmaxf(ai + aj - inter, 1e-12f);
      pred = (inter / den) > 0.5f;
    }
    ull bits = __ballot(pred);
    if (lane == 0) mask[(size_t)i*64 + w] = bits;
  }
}

// ---- serial greedy NMS scan (single wave) ----
#define CHUNK 16
__global__ __launch_bounds__(64) void nms_scan(const ull* __restrict__ mask,
                                               const int* __restrict__ Vp,
                                               const int* __restrict__ order,
                                               int* __restrict__ keep) {
  int lane = threadIdx.x;
  for (int idx = lane; idx < NBOX; idx += 64) keep[idx] = 0;
  __syncthreads();
  int V = *Vp;
  ull remw = 0;
  __shared__ ull buf[CHUNK][64];
  for (int base = 0; base < V; base += CHUNK) {
    int nn = min(CHUNK, V - base);
#pragma unroll
    for (int r = 0; r < CHUNK; ++r)
      if (r < nn) buf[r][lane] = mask[(size_t)(base + r)*64 + lane];
    for (int r = 0; r < nn; ++r) {
      int i = base + r;
      ull w = __shfl(remw, i >> 6, 64);
      if (!((w >> (i & 63)) & 1ull)) {
        remw |= buf[r][lane];
        if (lane == 0) keep[order[i]] = 1;
      }
    }
  }
}

__global__ __launch_bounds__(256) void out_kernel(const float* __restrict__ boxes,
                                                  const int* __restrict__ keep,
                                                  float* __restrict__ out) {
  int n = blockIdx.x * 256 + threadIdx.x;
  float4 b = *(const float4*)&boxes[n*4];
  float4 z = make_float4(0.f, 0.f, 0.f, 0.f);
  *(float4*)&out[n*4] = keep[n] ? b : z;
}

extern "C" void kernel_launch(void* const* d_in, const int* in_sizes, int n_in,
                              void* d_out, int out_size, void* d_ws, size_t ws_size,
                              hipStream_t stream) {
  const float* image  = (const float*)d_in[0];
  const float* bboxes = (const float*)d_in[1];
  const float* w1  = (const float*)d_in[2];
  const float* b1  = (const float*)d_in[3];
  const float* a1  = (const float*)d_in[4];
  const float* w2  = (const float*)d_in[5];
  const float* b2  = (const float*)d_in[6];
  const float* a2  = (const float*)d_in[7];
  const float* w3  = (const float*)d_in[8];
  const float* b3  = (const float*)d_in[9];
  const float* a3  = (const float*)d_in[10];
  const float* w4  = (const float*)d_in[11];
  const float* b4  = (const float*)d_in[12];
  const float* a4  = (const float*)d_in[13];
  const float* w5a = (const float*)d_in[14];
  const float* b5a = (const float*)d_in[15];
  const float* w5b = (const float*)d_in[16];
  const float* b5b = (const float*)d_in[17];

  char* ws = (char*)d_ws;
  float* boxes  = (float*)(ws + 0);        // 4096*4 f32
  float* scores = (float*)(ws + 65536);    // 4096 f32
  float* sboxes = (float*)(ws + 81920);    // 4096*4 f32 (sorted)
  int*   order  = (int*)  (ws + 147456);   // 4096 i32
  int*   Vp     = (int*)  (ws + 163840);   // 1 i32
  int*   keep   = (int*)  (ws + 163856);   // 4096 i32
  ull*   mask   = (ull*)  (ws + 180240);   // 4096*64 u64 -> ends 2277392
  unsigned short* wbt  = (unsigned short*)(ws + WS_BT);
  unsigned short* wbt1 = (unsigned short*)(ws + WS_BT1);

  float* out = (float*)d_out;

  wconv_kernel<<<17, 256, 0, stream>>>(w2, w1, wbt, wbt1);
  cnn_kernel<<<NBOX, 256, 0, stream>>>(image, bboxes, wbt1, b1,a1, wbt, b2,a2, w3,b3,a3,
                                       w4,b4,a4, w5a,b5a, w5b,b5b, boxes, scores);
  sort_kernel<<<1, 1024, 0, stream>>>(scores, boxes, order, sboxes, Vp);
  iou_kernel<<<NBOX, 256, 0, stream>>>(sboxes, Vp, mask);
  nms_scan<<<1, 64, 0, stream>>>(mask, Vp, order, keep);
  out_kernel<<<16, 256, 0, stream>>>(boxes, keep, out);
}

// Round 10
// 342.535 us; speedup vs baseline: 1.6778x; 1.1648x over previous
//
#include <hip/hip_runtime.h>

typedef unsigned long long ull;
typedef __attribute__((ext_vector_type(8))) short bf16x8;
typedef __attribute__((ext_vector_type(4))) float f32x4;

#define W_IMG 1920
#define H_IMG 1080
#define NBOX 4096

// ---- LDS layout (float offsets), total 6048 floats = 24192 B -> 6 blocks/CU ----
// crop bf16 [3][24][28] = 2016 sh = 1008 fl      @ fl [0, 1008)
// cbuf bf16 [28 co][228 pix pitch] = 6384 sh     @ fl [1008, 4200)   (conv1 raw out, per chunk)
// plane bf16 [11][12][28] = 3696 sh = 1848 fl    @ fl [4200, 6048)   (pool1 out, conv2 A)
// buf2 f32 [48][81] = 3888                       @ fl [0, 3888)      (crop+cbuf dead)
// pool2 f32 [48][16] = 768                       @ fl [3888, 4656)   (plane dead)
// feat f32 [576] @ [0,576) | vec [576,704) | lout [704,710)
#define S_CROP_SH 0        // short index
#define S_CBUF_SH 2016     // short index, pitch 228
#define S_PLANE_SH 8400    // short index
#define S_BUF2   0
#define S_POOL2  3888
#define S_FEAT   0
#define S_VEC    576
#define S_LOUT   704
#define SMEM_F   6048

#define WS_BT    2277392   // w2 bf16 plane: 13824 sh = 27648 B
#define WS_BT1   2305040   // w1 bf16 plane: 1024 sh = 2048 B

__device__ __forceinline__ float4 ld4(const float* p) { return *(const float4*)p; }
__device__ __forceinline__ float prelu_f(float v, float a) { return v > 0.f ? v : a * v; }
__device__ __forceinline__ unsigned short bf16rn(float v) {
  unsigned u = __float_as_uint(v);
  return (unsigned short)((u + 0x7fffu + ((u >> 16) & 1u)) >> 16);
}
__device__ __forceinline__ float bf16tof(unsigned short h) {
  return __uint_as_float(((unsigned)h) << 16);
}

// ---- pre-kernel: weight bf16 conversion (w2 -> bt, w1 -> bt1), single plane ----
// bt  layout: [kk(9)][co(48)][c(32)]   (c>=28 zero)
// bt1 layout: [grp(4)][co(32)][j(8)]   (k=grp*8+j >=27 zero, co>=28 zero)
__global__ __launch_bounds__(256) void wconv_kernel(const float* __restrict__ w2,
                                                    const float* __restrict__ w1,
                                                    unsigned short* __restrict__ bt,
                                                    unsigned short* __restrict__ bt1) {
  int b = blockIdx.x, tid = threadIdx.x;
  if (b < 16) {
    for (int e = b*864 + tid; e < (b+1)*864; e += 256) {   // e = (kk*48+co)*32 + c
      int c = e & 31, rest = e >> 5;
      int co = rest % 48, kk = rest / 48;
      float v = (c < 28) ? w2[co*252 + c*9 + kk] : 0.f;
      bt[e] = bf16rn(v);
    }
  } else {
    for (int e = tid; e < 1024; e += 256) {                // e = (grp*32+co)*8 + j
      int j = e & 7, rest = e >> 3;
      int co = rest & 31, grp = rest >> 5;
      int k = grp*8 + j;
      float v = (k < 27 && co < 28) ? w1[co*27 + k] : 0.f;
      bt1[e] = bf16rn(v);
    }
  }
}

__global__ __launch_bounds__(256, 6) void cnn_kernel(
    const float* __restrict__ image, const float* __restrict__ bboxes,
    const unsigned short* __restrict__ wbt1,
    const float* __restrict__ b1, const float* __restrict__ a1,
    const unsigned short* __restrict__ wbt,
    const float* __restrict__ b2, const float* __restrict__ a2,
    const float* __restrict__ w3, const float* __restrict__ b3, const float* __restrict__ a3,
    const float* __restrict__ w4, const float* __restrict__ b4, const float* __restrict__ a4,
    const float* __restrict__ w5a, const float* __restrict__ b5a,
    const float* __restrict__ w5b, const float* __restrict__ b5b,
    float* __restrict__ boxes, float* __restrict__ scores)
{
  __shared__ float sm[SMEM_F];
  __shared__ int s_ix[24], s_iy[24];
  const int tid = threadIdx.x;
  const int n = blockIdx.x;
  const float lo = -__builtin_inff();
  const int lane = tid & 63, wv = tid >> 6;
  const int grp = lane >> 4, lr = lane & 15;
  unsigned short* csh = (unsigned short*)sm;

  // ---- conv1 B-fragment preload (8 VGPR) ----
  bf16x8 c1B[2];
  {
    const bf16x8* btc = (const bf16x8*)wbt1;      // [grp*32 + co]
    c1B[0] = btc[grp*32 + lr];
    c1B[1] = btc[grp*32 + 16 + lr];
  }
  // per-lane A-build offsets: k = grp*8+j -> (c,ky,kx); off = c*672 + ky*28 + kx (shorts)
  int aoff[8];
#pragma unroll
  for (int j = 0; j < 8; ++j) {
    int k = grp*8 + j;
    int c = k / 9, rr = k - 9*c, ky = rr / 3, kx = rr - 3*ky;
    aoff[j] = c*672 + ky*28 + kx;
  }

  // ---- Phase A: crop indices + crop/normalize staging (bf16 shorts) ----
  if (tid < 24) {
    int x1 = min(max((int)bboxes[n*4+0], 0), W_IMG);
    int x2 = min(max((int)bboxes[n*4+2], 0), W_IMG);
    s_ix[tid] = min(max(x1 + (tid*(x2-x1))/24, 0), W_IMG-1);
  } else if (tid >= 64 && tid < 88) {
    int j = tid - 64;
    int y1 = min(max((int)bboxes[n*4+1], 0), H_IMG);
    int y2 = min(max((int)bboxes[n*4+3], 0), H_IMG);
    s_iy[j] = min(max(y1 + (j*(y2-y1))/24, 0), H_IMG-1);
  }
  __syncthreads();
  for (int e = tid; e < 1728; e += 256) {
    int c = e / 576, rr = e % 576, y = rr / 24, x = rr % 24;
    float v = image[(s_iy[y]*W_IMG + s_ix[x])*3 + c];
    csh[S_CROP_SH + c*672 + y*28 + x] = bf16rn((v - 127.5f) * 0.0078125f);
  }
  __syncthreads();

  // ---- Phase B: conv1 via MFMA (implicit im2col, K=27->32, N=28->32, single bf16),
  //      3 row-chunks; cbuf bf16 [co][pitch 228]; fused pool+prelu -> bf16 plane ----
  {
    unsigned short* cb = csh + S_CBUF_SH;
    unsigned short* pl = csh + S_PLANE_SH;
    const int c_r0[3] = {0, 7, 15};
    const int c_R [3] = {8, 9, 7};
    const int c_p0[3] = {0, 4, 8};
    const int c_np[3] = {4, 4, 3};
#pragma unroll 1
    for (int ck = 0; ck < 3; ++ck) {
      const int r0 = c_r0[ck], R = c_R[ck], p0 = c_p0[ck], np = c_np[ck];
      const int npix = R*22;
      const int mt = (npix + 15) >> 4;
#pragma unroll 1
      for (int t = wv; t < mt; t += 4) {
        int row = t*16 + lr;
        int pix = min(row, npix - 1);
        int ly = pix / 22;
        int x  = pix - ly*22;
        int base = (r0 + ly)*28 + x;
        unsigned short h1[8];
#pragma unroll
        for (int j = 0; j < 8; ++j)
          h1[j] = (grp*8 + j < 27) ? csh[base + aoff[j]] : (unsigned short)0;
        union { bf16x8 v; unsigned u[4]; } A1;
#pragma unroll
        for (int q = 0; q < 4; ++q)
          A1.u[q] = (unsigned)h1[2*q] | ((unsigned)h1[2*q+1] << 16);
        f32x4 acc0 = {0.f,0.f,0.f,0.f}, acc1 = {0.f,0.f,0.f,0.f};
        acc0 = __builtin_amdgcn_mfma_f32_16x16x32_bf16(A1.v, c1B[0], acc0, 0, 0, 0);
        acc1 = __builtin_amdgcn_mfma_f32_16x16x32_bf16(A1.v, c1B[1], acc1, 0, 0, 0);
        // C-write: col co = lr / 16+lr ; rows p0r..p0r+3 -> b64
        int p0r = t*16 + grp*4;
        union { ull d; unsigned short s[4]; } W;
#pragma unroll
        for (int r = 0; r < 4; ++r) W.s[r] = bf16rn(acc0[r]);
        *(ull*)(cb + lr*228 + p0r) = W.d;
        if (lr < 12) {
#pragma unroll
          for (int r = 0; r < 4; ++r) W.s[r] = bf16rn(acc1[r]);
          *(ull*)(cb + (16 + lr)*228 + p0r) = W.d;
        }
      }
      __syncthreads();
      // pool(3,2,pad1) rows p0..p0+np-1 + bias + prelu -> bf16 plane [y][x][c]
      const int npt = np * 308;            // o = pyl*308 + co*11 + px
      for (int o = tid; o < npt; o += 256) {
        int pyl = o / 308, rem = o - pyl*308;
        int co = rem / 11, px = rem - co*11;
        int py = p0 + pyl;
        int rlo = max(2*py - 1, 0) - r0, rhi = 2*py + 1 - r0;
        int clo = max(2*px - 1, 0), chi = min(2*px + 1, 21);
        float m = lo;
        for (int r = rlo; r <= rhi; ++r)
          for (int c2 = clo; c2 <= chi; ++c2)
            m = fmaxf(m, bf16tof(cb[co*228 + r*22 + c2]));
        float v = prelu_f(m + b1[co], a1[co]);
        pl[(py*12 + px)*28 + co] = bf16rn(v);
      }
      __syncthreads();
    }
  }

  // ---- Phase D: conv2 via MFMA 16x16x32 bf16, 9 shifted GEMMs (ky,kx), K=32 pad ----
  {
    const unsigned short* pl = csh + S_PLANE_SH;
    const bf16x8* bt = (const bf16x8*)wbt;      // [9][48][4] bf16x8
#pragma unroll 1
    for (int t = wv; t < 18; t += 4) {
      const int mtile = t / 3, ntile = t - 3*(t/3);
      const int co = ntile*16 + lr;
      const int arow = min(mtile*16 + lr, 80);
      const int oy = (arow*57) >> 9;
      const int ox = arow - 9*oy;
      const int pixb = (oy*12 + ox)*28 + grp*8;
      f32x4 acc = {0.f, 0.f, 0.f, 0.f};
#pragma unroll
      for (int kk = 0; kk < 9; ++kk) {
        const int ky = kk / 3, kx = kk - 3*(kk/3);
        const int aoff2 = pixb + (ky*12 + kx)*28;
        union { bf16x8 v; ull d[2]; } A1;
        A1.d[0] = *(const ull*)(pl + aoff2);
        A1.d[1] = *(const ull*)(pl + aoff2 + 4);
        const bf16x8 B1 = bt[(kk*48 + co)*4 + grp];
        acc = __builtin_amdgcn_mfma_f32_16x16x32_bf16(A1.v, B1, acc, 0, 0, 0);
      }
      const float bb = b2[co], aa = a2[co];
      const int p0 = mtile*16 + grp*4;
#pragma unroll
      for (int r = 0; r < 4; ++r) {
        int p = p0 + r;
        if (p < 81) sm[S_BUF2 + co*81 + p] = prelu_f(acc[r] + bb, aa);
      }
    }
  }
  __syncthreads();

  // ---- Phase E: pool2 (3,2,pad0) full 48 channels ----
  for (int o = tid; o < 768; o += 256) {
    int cl = o >> 4, rem = o & 15, pyy = rem >> 2, pxx = rem & 3;
    float m = lo;
#pragma unroll
    for (int ky = 0; ky < 3; ++ky)
#pragma unroll
      for (int kx = 0; kx < 3; ++kx)
        m = fmaxf(m, sm[S_BUF2 + cl*81 + (2*pyy+ky)*9 + (2*pxx+kx)]);
    sm[S_POOL2 + o] = m;
  }
  __syncthreads();

  // ---- Phase F: conv3 (2x2, 48->64) -> feat[576] ----
  {
    int co = tid >> 2, c4 = tid & 3;
    float acc[9] = {};
    for (int cc = 0; cc < 12; ++cc) {
      int c = c4*12 + cc;
      float r[16];
      *(float4*)&r[0]  = ld4(sm + S_POOL2 + c*16);
      *(float4*)&r[4]  = ld4(sm + S_POOL2 + c*16 + 4);
      *(float4*)&r[8]  = ld4(sm + S_POOL2 + c*16 + 8);
      *(float4*)&r[12] = ld4(sm + S_POOL2 + c*16 + 12);
      float4 wq = ld4(&w3[co*192 + c*4]);
#pragma unroll
      for (int p = 0; p < 9; ++p) {
        int pyy = p / 3, pxx = p % 3;
        acc[p] += r[pyy*4+pxx]*wq.x + r[pyy*4+pxx+1]*wq.y
                + r[(pyy+1)*4+pxx]*wq.z + r[(pyy+1)*4+pxx+1]*wq.w;
      }
    }
#pragma unroll
    for (int p = 0; p < 9; ++p) {
      acc[p] += __shfl_xor(acc[p], 1, 64);
      acc[p] += __shfl_xor(acc[p], 2, 64);
    }
    if (c4 == 0) {
      float bb = b3[co], aa = a3[co];
#pragma unroll
      for (int p = 0; p < 9; ++p) sm[S_FEAT + co*9 + p] = prelu_f(acc[p] + bb, aa);
    }
  }
  __syncthreads();

  // ---- Phase G: lin4 (576->128) + prelu ----
  {
    for (int f = wv; f < 128; f += 4) {
      const float* wr = w4 + f*576;
      float acc = 0.f;
#pragma unroll
      for (int i = 0; i < 9; ++i) {
        int j = i*64 + lane;
        acc += wr[j] * sm[S_FEAT + j];
      }
#pragma unroll
      for (int off = 1; off < 64; off <<= 1) acc += __shfl_xor(acc, off, 64);
      if (lane == 0) sm[S_VEC + f] = prelu_f(acc + b4[f], a4[f]);
    }
  }
  __syncthreads();

  // ---- Phase H: lin5a (softmax) + lin5b (reg) + box regression ----
  if (tid < 6) {
    const float* wr = (tid < 2) ? (w5a + tid*128) : (w5b + (tid-2)*128);
    float acc = 0.f;
#pragma unroll
    for (int j = 0; j < 32; ++j) {
      float4 xv = ld4(sm + S_VEC + j*4);
      float4 wv = ld4(wr + j*4);
      acc += xv.x*wv.x + xv.y*wv.y + xv.z*wv.z + xv.w*wv.w;
    }
    acc += (tid < 2) ? b5a[tid] : b5b[tid-2];
    sm[S_LOUT + tid] = acc;
  }
  __syncthreads();
  if (tid == 0) {
    float l0 = sm[S_LOUT+0], l1 = sm[S_LOUT+1];
    float m = fmaxf(l0, l1);
    float e0 = expf(l0 - m), e1 = expf(l1 - m);
    float sc = e1 / (e0 + e1);
    float4 bb = ld4(&bboxes[n*4]);
    float bw = bb.z - bb.x, bh = bb.w - bb.y;
    float4 ob = make_float4(bb.x + sm[S_LOUT+2]*bw, bb.y + sm[S_LOUT+3]*bh,
                            bb.z + sm[S_LOUT+4]*bw, bb.w + sm[S_LOUT+5]*bh);
    *(float4*)&boxes[n*4] = ob;
    scores[n] = sc;
  }
}

// ---- sort by (-score, idx) via bitonic; early-exit when no valid boxes ----
__global__ __launch_bounds__(1024) void sort_kernel(const float* __restrict__ scores,
                                                    const float* __restrict__ boxes,
                                                    int* __restrict__ order,
                                                    float* __restrict__ sboxes,
                                                    int* __restrict__ Vp) {
  __shared__ ull keys[NBOX];
  __shared__ int cnt;
  int tid = threadIdx.x;
  if (tid == 0) cnt = 0;
  __syncthreads();
  int local = 0;
  for (int i = tid; i < NBOX; i += 1024) {
    float s = scores[i];
    bool valid = (s >= 0.7f);
    unsigned hi = valid ? (0xFFFFFFFFu - __float_as_uint(s)) : 0xFFFFFFFFu;
    keys[i] = ((ull)hi << 32) | (unsigned)i;
    if (valid) local++;
  }
  atomicAdd(&cnt, local);
  __syncthreads();
  if (tid == 0) *Vp = cnt;
  if (cnt == 0) return;
  for (int k = 2; k <= NBOX; k <<= 1) {
    for (int j = k >> 1; j > 0; j >>= 1) {
      __syncthreads();
      for (int i = tid; i < NBOX; i += 1024) {
        int ij = i ^ j;
        if (ij > i) {
          ull a = keys[i], b = keys[ij];
          bool up = ((i & k) == 0);
          if ((a > b) == up) { keys[i] = b; keys[ij] = a; }
        }
      }
    }
  }
  __syncthreads();
  for (int i = tid; i < NBOX; i += 1024) {
    int idx = (int)(unsigned)(keys[i] & 0xFFFFFFFFu);
    order[i] = idx;
    *(float4*)&sboxes[i*4] = *(const float4*)&boxes[idx*4];
  }
}

// ---- pairwise IoU suppression bitmask ----
__global__ __launch_bounds__(256) void iou_kernel(const float* __restrict__ sboxes,
                                                  const int* __restrict__ Vp,
                                                  ull* __restrict__ mask) {
  int i = blockIdx.x;
  int V = *Vp;
  if (i >= V) return;
  float4 bi = *(const float4*)&sboxes[i*4];
  float ai = fmaxf(bi.z - bi.x, 0.f) * fmaxf(bi.w - bi.y, 0.f);
  int lane = threadIdx.x & 63;
  for (int w = threadIdx.x >> 6; w < 64; w += 4) {
    int j = (w << 6) | lane;
    bool pred = false;
    if (j > i && j < V) {
      float4 bj = *(const float4*)&sboxes[j*4];
      float aj = fmaxf(bj.z - bj.x, 0.f) * fmaxf(bj.w - bj.y, 0.f);
      float xx1 = fmaxf(bi.x, bj.x), yy1 = fmaxf(bi.y, bj.y);
      float xx2 = fminf(bi.z, bj.z), yy2 = fminf(bi.w, bj.w);
      float inter = fmaxf(xx2 - xx1, 0.f) * fmaxf(yy2 - yy1, 0.f);
      float den = fmaxf(ai + aj - inter, 1e-12f);
      pred = (inter / den) > 0.5f;
    }
    ull bits = __ballot(pred);
    if (lane == 0) mask[(size_t)i*64 + w] = bits;
  }
}

// ---- serial greedy NMS scan + masked output write (single wave) ----
#define CHUNK 16
__global__ __launch_bounds__(64) void nms_out(const ull* __restrict__ mask,
                                              const int* __restrict__ Vp,
                                              const int* __restrict__ order,
                                              const float* __restrict__ boxes,
                                              float* __restrict__ out) {
  __shared__ ull buf[CHUNK][64];
  __shared__ int klist[NBOX];
  __shared__ int kc;
  int lane = threadIdx.x;
  if (lane == 0) kc = 0;
  float4 z = make_float4(0.f, 0.f, 0.f, 0.f);
  for (int i = lane; i < NBOX; i += 64) *(float4*)&out[i*4] = z;
  __syncthreads();
  int V = *Vp;
  ull remw = 0;
  for (int base = 0; base < V; base += CHUNK) {
    int nn = min(CHUNK, V - base);
#pragma unroll
    for (int r = 0; r < CHUNK; ++r)
      if (r < nn) buf[r][lane] = mask[(size_t)(base + r)*64 + lane];
    for (int r = 0; r < nn; ++r) {
      int i = base + r;
      ull w = __shfl(remw, i >> 6, 64);
      if (!((w >> (i & 63)) & 1ull)) {
        remw |= buf[r][lane];
        if (lane == 0) klist[kc++] = order[i];
      }
    }
  }
  __syncthreads();
  for (int j = lane; j < kc; j += 64) {
    int oi = klist[j];
    *(float4*)&out[oi*4] = *(const float4*)&boxes[oi*4];
  }
}

extern "C" void kernel_launch(void* const* d_in, const int* in_sizes, int n_in,
                              void* d_out, int out_size, void* d_ws, size_t ws_size,
                              hipStream_t stream) {
  const float* image  = (const float*)d_in[0];
  const float* bboxes = (const float*)d_in[1];
  const float* w1  = (const float*)d_in[2];
  const float* b1  = (const float*)d_in[3];
  const float* a1  = (const float*)d_in[4];
  const float* w2  = (const float*)d_in[5];
  const float* b2  = (const float*)d_in[6];
  const float* a2  = (const float*)d_in[7];
  const float* w3  = (const float*)d_in[8];
  const float* b3  = (const float*)d_in[9];
  const float* a3  = (const float*)d_in[10];
  const float* w4  = (const float*)d_in[11];
  const float* b4  = (const float*)d_in[12];
  const float* a4  = (const float*)d_in[13];
  const float* w5a = (const float*)d_in[14];
  const float* b5a = (const float*)d_in[15];
  const float* w5b = (const float*)d_in[16];
  const float* b5b = (const float*)d_in[17];

  char* ws = (char*)d_ws;
  float* boxes  = (float*)(ws + 0);        // 4096*4 f32
  float* scores = (float*)(ws + 65536);    // 4096 f32
  float* sboxes = (float*)(ws + 81920);    // 4096*4 f32 (sorted)
  int*   order  = (int*)  (ws + 147456);   // 4096 i32
  int*   Vp     = (int*)  (ws + 163840);   // 1 i32
  ull*   mask   = (ull*)  (ws + 180240);   // 4096*64 u64 -> ends 2277392
  unsigned short* wbt  = (unsigned short*)(ws + WS_BT);
  unsigned short* wbt1 = (unsigned short*)(ws + WS_BT1);

  float* out = (float*)d_out;

  wconv_kernel<<<17, 256, 0, stream>>>(w2, w1, wbt, wbt1);
  cnn_kernel<<<NBOX, 256, 0, stream>>>(image, bboxes, wbt1, b1,a1, wbt, b2,a2, w3,b3,a3,
                                       w4,b4,a4, w5a,b5a, w5b,b5b, boxes, scores);
  sort_kernel<<<1, 1024, 0, stream>>>(scores, boxes, order, sboxes, Vp);
  iou_kernel<<<NBOX, 256, 0, stream>>>(sboxes, Vp, mask);
  nms_out<<<1, 64, 0, stream>>>(mask, Vp, order, boxes, out);
}